// Round 1
// baseline (4802.742 us; speedup 1.0000x reference)
//
#include <hip/hip_runtime.h>
#include <hip/hip_bf16.h>

typedef short s16x8 __attribute__((ext_vector_type(8)));
typedef float f32x4 __attribute__((ext_vector_type(4)));
typedef unsigned short u16;
typedef unsigned short u16x4 __attribute__((ext_vector_type(4)));

__device__ __forceinline__ u16 f2bf(float f) {
  __hip_bfloat16 h = __float2bfloat16(f);
  u16 u;
  __builtin_memcpy(&u, &h, sizeof(u));
  return u;
}

// ---------------------------------------------------------------------------
// Generic bf16 MFMA GEMM:  C[m,n] = act( sum_k A[m,k]*B[n,k] + bias[n] )
// A: [.., lda] bf16 (rows optionally gathered via ids), B: [.., ldb] bf16
// 128x128 tile, BK=32, 256 threads (4 waves, 2x2 wave grid, 4x4 16x16 frags).
// Batched via blockIdx.z strides. C row remap: crow=(m/rpb)*cbs + (m%rpb)*ldc.
// Requirements: K%32==0; A rows allocated >= gridY*128 (per batch); B rows
// allocated >= gridX*128 (per batch). C writes masked to m<M, n<N.
// ---------------------------------------------------------------------------
template<int CBF16, int GATHER, int TANHA, int BIAS>
__global__ __launch_bounds__(256) void gemm_bt(
    const u16* __restrict__ A, const u16* __restrict__ B,
    const float* __restrict__ bias, void* __restrict__ Cv,
    const int* __restrict__ ids,
    int M, int N, int K, int lda, int ldb, int ldc,
    long sAz, long sBz, long sCz, int rpb, long cbs)
{
  __shared__ u16 sA[4096];
  __shared__ u16 sB[4096];
  const int tid = threadIdx.x;
  const int z = blockIdx.z;
  const int m0 = blockIdx.y * 128, n0 = blockIdx.x * 128;
  const u16* Ab = A + z * sAz;
  const u16* Bb = B + z * sBz;
  const int w = tid >> 6, lane = tid & 63;
  const int wr = w >> 1, wc = w & 1;
  const int lr = lane & 15, lk = lane >> 4;
  f32x4 acc[4][4] = {};
  const int e0 = tid * 8, e1 = e0 + 2048;
  const int r0 = e0 >> 5, c0 = e0 & 31;
  const int r1 = e1 >> 5, c1 = e1 & 31;
  long arow0, arow1;
  if (GATHER) {
    int i0 = m0 + r0; if (i0 >= M) i0 = M - 1;
    int i1 = m0 + r1; if (i1 >= M) i1 = M - 1;
    arow0 = (long)ids[i0] * lda;
    arow1 = (long)ids[i1] * lda;
  } else {
    arow0 = (long)(m0 + r0) * lda;
    arow1 = (long)(m0 + r1) * lda;
  }
  const long brow0 = (long)(n0 + r0) * ldb;
  const long brow1 = (long)(n0 + r1) * ldb;
  for (int kt = 0; kt < K; kt += 32) {
    __syncthreads();
    *(s16x8*)&sA[e0] = *(const s16x8*)&Ab[arow0 + kt + c0];
    *(s16x8*)&sA[e1] = *(const s16x8*)&Ab[arow1 + kt + c1];
    *(s16x8*)&sB[e0] = *(const s16x8*)&Bb[brow0 + kt + c0];
    *(s16x8*)&sB[e1] = *(const s16x8*)&Bb[brow1 + kt + c1];
    __syncthreads();
    s16x8 af[4], bf[4];
#pragma unroll
    for (int i = 0; i < 4; i++) {
      af[i] = *(const s16x8*)&sA[(wr*64 + i*16 + lr)*32 + lk*8];
      bf[i] = *(const s16x8*)&sB[(wc*64 + i*16 + lr)*32 + lk*8];
    }
#pragma unroll
    for (int mi = 0; mi < 4; mi++)
#pragma unroll
      for (int ni = 0; ni < 4; ni++)
        acc[mi][ni] = __builtin_amdgcn_mfma_f32_16x16x32_bf16(af[mi], bf[ni], acc[mi][ni], 0, 0, 0);
  }
#pragma unroll
  for (int mi = 0; mi < 4; mi++) {
#pragma unroll
    for (int ni = 0; ni < 4; ni++) {
#pragma unroll
      for (int r = 0; r < 4; r++) {
        int gm = m0 + wr*64 + mi*16 + lk*4 + r;
        int gn = n0 + wc*64 + ni*16 + lr;
        if (gm < M && gn < N) {
          float v = acc[mi][ni][r];
          if (BIAS) v += bias[gn];
          if (TANHA) v = tanhf(v);
          long ci = z * sCz + (long)(gm / rpb) * cbs + (long)(gm % rpb) * ldc + gn;
          if (CBF16) ((u16*)Cv)[ci] = f2bf(v);
          else       ((float*)Cv)[ci] = v;
        }
      }
    }
  }
}

// ---------------------------------------------------------------------------
// fp32 -> bf16 cast with zero padding beyond src rows/cols.
// grid: (ceil(dcols/256), drows)
// ---------------------------------------------------------------------------
__global__ __launch_bounds__(256) void cast_pad(
    const float* __restrict__ src, u16* __restrict__ dst,
    int srows, int scols, int slda, int dcols)
{
  int r = blockIdx.y;
  int c = blockIdx.x * 256 + threadIdx.x;
  if (c >= dcols) return;
  float v = (r < srows && c < scols) ? src[(long)r * slda + c] : 0.f;
  dst[(long)r * dcols + c] = f2bf(v);
}

// init LSTM states (buf0): h for l=0,1 and c for l=0,1
__global__ __launch_bounds__(256) void init_k(
    const float* __restrict__ h0, const float* __restrict__ c0,
    float* __restrict__ hstate, float* __restrict__ cstate)
{
  int i = blockIdx.x * 256 + threadIdx.x;
  if (i < 6144) {
    hstate[i] = h0[i];
    hstate[6144 + i] = h0[i];
    cstate[i] = c0[i];
    cstate[6144 + i] = c0[i];
  }
}

// ---------------------------------------------------------------------------
// One LSTM timestep for both LSTMs (l=0 edits, l=1 words).
// grid 192 = 2 l * 96 jb; 256 thr = kq(4) x jl(8) x b(8). 4-way K-split +
// LDS reduce. fp32 Whh streamed from L2; h double-buffered across launches
// (hsrc/hdst) to avoid cross-WG races.
// ---------------------------------------------------------------------------
__global__ __launch_bounds__(256) void lstm_step(
    const float* __restrict__ Whh_e, const float* __restrict__ Whh_w,
    const float* __restrict__ xW_e, const float* __restrict__ xW_w,
    const float* __restrict__ hsrc, float* __restrict__ hdst,
    float* __restrict__ cstate,
    u16* __restrict__ out_e, u16* __restrict__ out_w, int t)
{
  const int l = blockIdx.x / 96, jb = blockIdx.x % 96;
  const int tid = threadIdx.x;
  const int kq = tid >> 6;
  const int jl = (tid >> 3) & 7;
  const int b = tid & 7;
  const int j = jb * 8 + jl;
  const float* W = l ? Whh_w : Whh_e;
  const float* h = hsrc + l * 6144 + b * 768 + kq * 192;
  const float* w0 = W + (long)j * 768 + kq * 192;
  const float* w1 = w0 + 589824;   // +768*768
  const float* w2 = w1 + 589824;
  const float* w3 = w2 + 589824;
  float a0 = 0.f, a1 = 0.f, a2 = 0.f, a3 = 0.f;
#pragma unroll 4
  for (int k = 0; k < 192; k += 4) {
    float4 hv = *(const float4*)(h + k);
    float4 x0 = *(const float4*)(w0 + k);
    float4 x1 = *(const float4*)(w1 + k);
    float4 x2 = *(const float4*)(w2 + k);
    float4 x3 = *(const float4*)(w3 + k);
    a0 += x0.x*hv.x + x0.y*hv.y + x0.z*hv.z + x0.w*hv.w;
    a1 += x1.x*hv.x + x1.y*hv.y + x1.z*hv.z + x1.w*hv.w;
    a2 += x2.x*hv.x + x2.y*hv.y + x2.z*hv.z + x2.w*hv.w;
    a3 += x3.x*hv.x + x3.y*hv.y + x3.z*hv.z + x3.w*hv.w;
  }
  __shared__ float red[64][4][4];
  const int p = jl * 8 + b;
  red[p][0][kq] = a0; red[p][1][kq] = a1;
  red[p][2][kq] = a2; red[p][3][kq] = a3;
  __syncthreads();
  if (kq == 0) {
    float gi = red[p][0][0] + red[p][0][1] + red[p][0][2] + red[p][0][3];
    float gf = red[p][1][0] + red[p][1][1] + red[p][1][2] + red[p][1][3];
    float gg = red[p][2][0] + red[p][2][1] + red[p][2][2] + red[p][2][3];
    float go = red[p][3][0] + red[p][3][1] + red[p][3][2] + red[p][3][3];
    const float* xr = l ? (xW_w + ((long)b * 257 + t) * 3072)
                        : (xW_e + ((long)b * 256 + t) * 3072);
    gi += xr[j]; gf += xr[768 + j]; gg += xr[1536 + j]; go += xr[2304 + j];
    float si = 1.f / (1.f + expf(-gi));
    float sf = 1.f / (1.f + expf(-gf));
    float so = 1.f / (1.f + expf(-go));
    const int ci = l * 6144 + b * 768 + j;
    float c2 = sf * cstate[ci] + si * tanhf(gg);
    float h2 = so * tanhf(c2);
    cstate[ci] = c2;
    hdst[ci] = h2;
    (l ? out_w : out_e)[((long)b * 256 + t) * 768 + j] = f2bf(h2);
  }
}

// counter recurrence: 8 lanes scan 255 steps (pre-update ki/an recorded)
__global__ void counters_k(const int* __restrict__ input_edits,
                           const int* __restrict__ org_ids,
                           int* __restrict__ ki_bt, int* __restrict__ an_bt)
{
  int b = threadIdx.x;
  if (b >= 8) return;
  int kd = 0, ki = 0, an = 0;
  for (int t = 0; t < 255; t++) {
    int a = input_edits[b * 256 + t + 1];
    ki_bt[b * 255 + t] = ki;
    an_bt[b * 255 + t] = an;
    int kd2 = kd + ((a == 1) || (a == 2) ? 1 : 0);
    int ns = (a != 2) && (a != 102) && (a != 0);
    int ki2 = ki + (ns ? 1 : 0);
    int is_ins = ns && (a != 1);
    int nia = (org_ids[b * 257 + an + 1] == 103);
    int mx = (kd2 > an) ? kd2 : an;
    int an2 = (is_ins && nia) ? (an + 1) : mx;
    kd = kd2; ki = ki2; an = an2;
  }
}

// softmax over s (257 valid of 288) per (b,t) row; writes bf16 attn, zero pad
__global__ __launch_bounds__(256) void softmax_k(
    const float* __restrict__ scores, u16* __restrict__ attn)
{
  const int row = blockIdx.x;                 // 0..2047
  const float* src = scores + (long)row * 288;
  u16* dst = attn + (long)row * 288;
  const int tid = threadIdx.x;
  float v0 = (tid < 257) ? src[tid] : -1e30f;
  float v1 = (tid + 256 < 257) ? src[tid + 256] : -1e30f;
  float mx = fmaxf(v0, v1);
  for (int o = 32; o; o >>= 1) mx = fmaxf(mx, __shfl_xor(mx, o));
  __shared__ float sm[4];
  __shared__ float ss[4];
  if ((tid & 63) == 0) sm[tid >> 6] = mx;
  __syncthreads();
  mx = fmaxf(fmaxf(sm[0], sm[1]), fmaxf(sm[2], sm[3]));
  float e0 = (tid < 257) ? expf(v0 - mx) : 0.f;
  float e1 = (tid + 256 < 257) ? expf(v1 - mx) : 0.f;
  float s = e0 + e1;
  for (int o = 32; o; o >>= 1) s += __shfl_xor(s, o);
  if ((tid & 63) == 0) ss[tid >> 6] = s;
  __syncthreads();
  s = ss[0] + ss[1] + ss[2] + ss[3];
  float inv = 1.f / s;
  dst[tid] = f2bf(e0 * inv);
  if (tid + 256 < 288) dst[tid + 256] = f2bf(e1 * inv);
}

// enc_bf [8][384][768] -> encT_bf [8][768][288] (zero pad s>=257)
__global__ __launch_bounds__(256) void transpose_enc(
    const u16* __restrict__ enc, u16* __restrict__ encT)
{
  __shared__ u16 tile[32][33];
  const int b = blockIdx.z, h0 = blockIdx.y * 32, s0 = blockIdx.x * 32;
  const int tx = threadIdx.x & 31, ty = threadIdx.x >> 5;  // ty 0..7
#pragma unroll
  for (int i = 0; i < 32; i += 8) {
    int s = s0 + ty + i;
    u16 v = (s < 257) ? enc[((long)b * 384 + s) * 768 + h0 + tx] : (u16)0;
    tile[ty + i][tx] = v;
  }
  __syncthreads();
#pragma unroll
  for (int i = 0; i < 32; i += 8) {
    int h = h0 + ty + i;
    encT[((long)b * 768 + h) * 288 + s0 + tx] = tile[tx][ty + i];
  }
}

// feat[2048][3072] bf16 = [out_edits | ctx | enc(an) | out_words(ki)], 0-pad
__global__ __launch_bounds__(256) void feat_k(
    const u16* __restrict__ oute, const u16* __restrict__ ctx,
    const u16* __restrict__ encb, const u16* __restrict__ outw,
    const int* __restrict__ ki_bt, const int* __restrict__ an_bt,
    u16* __restrict__ feat)
{
  int q = blockIdx.x * 256 + threadIdx.x;       // < 1572864 (u16x4 units)
  int m = q / 768, qq = q - m * 768;
  int seg = qq / 192, off = (qq - seg * 192) * 4;
  u16x4 v = {0, 0, 0, 0};
  if (m < 2040) {
    int b = m / 255, t = m - b * 255;
    const u16* src;
    if (seg == 0)      src = oute + ((long)(b * 256 + t)) * 768 + off;
    else if (seg == 1) src = ctx  + ((long)(b * 256 + t)) * 768 + off;
    else if (seg == 2) src = encb + ((long)(b * 384 + an_bt[m])) * 768 + off;
    else               src = outw + ((long)(b * 256 + ki_bt[m])) * 768 + off;
    v = *(const u16x4*)src;
  }
  *(u16x4*)(feat + (long)q * 4) = v;
}

// online max/sum-exp per logits row -> rowstat = max + log(sumexp)
__global__ __launch_bounds__(256) void rowstat_k(
    const float* __restrict__ logits, float* __restrict__ rowstat)
{
  const int m = blockIdx.x;
  const float* row = logits + (long)m * 21128;
  const int tid = threadIdx.x;
  float mx = -1e30f, sm = 0.f;
  for (int i = tid * 4; i < 21128; i += 1024) {
    float4 v = *(const float4*)(row + i);
    float m4 = fmaxf(fmaxf(v.x, v.y), fmaxf(v.z, v.w));
    if (m4 > mx) { sm *= expf(mx - m4); mx = m4; }
    sm += expf(v.x - mx) + expf(v.y - mx) + expf(v.z - mx) + expf(v.w - mx);
  }
  for (int o = 32; o; o >>= 1) {
    float mo = __shfl_xor(mx, o), so = __shfl_xor(sm, o);
    float nm = fmaxf(mx, mo);
    sm = sm * expf(mx - nm) + so * expf(mo - nm);
    mx = nm;
  }
  __shared__ float wm[4], wsum[4];
  if ((tid & 63) == 0) { wm[tid >> 6] = mx; wsum[tid >> 6] = sm; }
  __syncthreads();
  if (tid == 0) {
    float M = wm[0], S = wsum[0];
    for (int i = 1; i < 4; i++) {
      float nm = fmaxf(M, wm[i]);
      S = S * expf(M - nm) + wsum[i] * expf(wm[i] - nm);
      M = nm;
    }
    rowstat[m] = M + logf(S);
  }
}

// in-place logp = logit - rowstat[row]
__global__ __launch_bounds__(256) void finalize_k(
    float* __restrict__ logits, const float* __restrict__ rowstat)
{
  long i4 = (long)blockIdx.x * 256 + threadIdx.x;
  if (i4 >= 10775280L) return;
  long i = i4 * 4;
  int m = (int)(i / 21128);
  float rs = rowstat[m];
  float4* p = (float4*)(logits + i);
  float4 v = *p;
  v.x -= rs; v.y -= rs; v.z -= rs; v.w -= rs;
  *p = v;
}

// copy hT (edits h state, buf0 l=0) and cT into d_out tail
__global__ __launch_bounds__(256) void tail_k(
    const float* __restrict__ hstate, const float* __restrict__ cstate,
    float* __restrict__ out)
{
  int i = blockIdx.x * 256 + threadIdx.x;
  if (i < 6144) {
    out[43101120 + i] = hstate[i];
    out[43107264 + i] = cstate[i];
  }
}

// ---------------------------------------------------------------------------
extern "C" void kernel_launch(void* const* d_in, const int* in_sizes, int n_in,
                              void* d_out, int out_size, void* d_ws, size_t ws_size,
                              hipStream_t stream) {
  (void)in_sizes; (void)n_in; (void)out_size; (void)ws_size;
  const int*   input_edits = (const int*)d_in[0];
  const int*   org_ids     = (const int*)d_in[1];
  const int*   simp_sent   = (const int*)d_in[2];
  const float* h0      = (const float*)d_in[3];
  const float* c0      = (const float*)d_in[4];
  const float* encoder = (const float*)d_in[5];
  const float* emb     = (const float*)d_in[6];
  const float* Wih_e   = (const float*)d_in[7];
  const float* Whh_e   = (const float*)d_in[8];
  const float* b_e     = (const float*)d_in[9];
  const float* Wih_w   = (const float*)d_in[10];
  const float* Whh_w   = (const float*)d_in[11];
  const float* b_w     = (const float*)d_in[12];
  const float* W_attn  = (const float*)d_in[13];
  const float* W_align = (const float*)d_in[14];
  const float* W_mlp   = (const float*)d_in[15];
  const float* b_mlp   = (const float*)d_in[16];
  const float* W_out   = (const float*)d_in[17];
  const float* b_out   = (const float*)d_in[18];

  float* out = (float*)d_out;
  // --- d_out region doubles as scratch until the logits GEMM overwrites it
  float* xW_e = out;                               // [2048][3072] f32
  float* xW_w = out + 2048L * 3072;                // [2056][3072] f32
  u16* emb_bf  = (u16*)(out + 2048L * 3072 + 2056L * 3072);  // [21128][768]
  u16* encd_bf = emb_bf + 21128L * 768;            // [2176][768] (pad rows 0)
  u16* feat_bf = encd_bf + 2176L * 768;            // [2048][3072]

  // --- ws scratch (~77 MB high-water)
  char* p = (char*)d_ws;
  auto alloc = [&](size_t bytes) -> char* {
    char* r = p; p += (bytes + 255) & ~(size_t)255; return r;
  };
  u16* Wout_bf   = (u16*)alloc(21248L * 768 * 2);
  u16* Wihe_bf   = (u16*)alloc(3072L * 768 * 2);
  u16* Wihw_bf   = (u16*)alloc(3072L * 768 * 2);
  u16* Wmlp_bf   = (u16*)alloc(768L * 3072 * 2);
  u16* Walign_bf = (u16*)alloc(768L * 768 * 2);
  u16* Wattn_bf  = (u16*)alloc(768L * 768 * 2);
  u16* enc_bf    = (u16*)alloc(8L * 384 * 768 * 2);   // padded batch stride
  u16* encT_bf   = (u16*)alloc(8L * 768 * 288 * 2);   // K padded to 288
  u16* oute_bf   = (u16*)alloc(2048L * 768 * 2);
  u16* outw_bf   = (u16*)alloc(2048L * 768 * 2);
  u16* key_bf    = (u16*)alloc(2048L * 768 * 2);
  u16* attn_bf   = (u16*)alloc(8L * 256 * 288 * 2);
  u16* ctx_bf    = (u16*)alloc(2048L * 768 * 2);
  u16* mlp_bf    = (u16*)alloc(2048L * 768 * 2);
  float* scores  = (float*)alloc(8L * 256 * 288 * 4);
  float* hstate  = (float*)alloc(2L * 2 * 6144 * 4);  // [buf][l][6144]
  float* cstate  = (float*)alloc(2L * 6144 * 4);      // [l][6144]
  int* ki_bt     = (int*)alloc(2040 * 4);
  int* an_bt     = (int*)alloc(2040 * 4);
  float* rowstat = (float*)alloc(2048 * 4);

  dim3 blk(256);
  const int BIGR = 1 << 30;

  // --- casts (fp32 -> bf16, with padding)
  cast_pad<<<dim3(3, 21128), blk, 0, stream>>>(emb, emb_bf, 21128, 768, 768, 768);
  cast_pad<<<dim3(3, 21248), blk, 0, stream>>>(W_out, Wout_bf, 21128, 768, 768, 768);
  cast_pad<<<dim3(3, 3072), blk, 0, stream>>>(Wih_e, Wihe_bf, 3072, 768, 768, 768);
  cast_pad<<<dim3(3, 3072), blk, 0, stream>>>(Wih_w, Wihw_bf, 3072, 768, 768, 768);
  cast_pad<<<dim3(12, 768), blk, 0, stream>>>(W_mlp, Wmlp_bf, 768, 3072, 3072, 3072);
  cast_pad<<<dim3(3, 768), blk, 0, stream>>>(W_align, Walign_bf, 768, 768, 768, 768);
  cast_pad<<<dim3(3, 768), blk, 0, stream>>>(W_attn, Wattn_bf, 768, 768, 768, 768);
  cast_pad<<<dim3(3, 2176), blk, 0, stream>>>(encoder, encd_bf, 2056, 768, 768, 768);
  init_k<<<24, blk, 0, stream>>>(h0, c0, hstate, cstate);
  counters_k<<<1, 64, 0, stream>>>(input_edits, org_ids, ki_bt, an_bt);

  // --- enc = tanh(encoder @ W_align^T) -> bf16, padded [8][384][768] layout
  gemm_bt<1, 0, 1, 0><<<dim3(6, 17, 1), blk, 0, stream>>>(
      encd_bf, Walign_bf, nullptr, enc_bf, nullptr,
      2056, 768, 768, 768, 768, 768, 0, 0, 0, 257, 294912L);

  // --- hoisted LSTM input projections (embedding gather + bias)
  gemm_bt<0, 1, 0, 1><<<dim3(24, 16, 1), blk, 0, stream>>>(
      emb_bf, Wihe_bf, b_e, xW_e, input_edits,
      2048, 3072, 768, 768, 768, 3072, 0, 0, 0, BIGR, 0);
  gemm_bt<0, 1, 0, 1><<<dim3(24, 17, 1), blk, 0, stream>>>(
      emb_bf, Wihw_bf, b_w, xW_w, simp_sent,
      2056, 3072, 768, 768, 768, 3072, 0, 0, 0, BIGR, 0);

  // --- sequential recurrences, both LSTMs per launch
  for (int t = 0; t < 256; t++) {
    lstm_step<<<dim3(192), blk, 0, stream>>>(
        Whh_e, Whh_w, xW_e, xW_w,
        hstate + (t & 1) * 12288, hstate + ((t + 1) & 1) * 12288,
        cstate, oute_bf, outw_bf, t);
  }

  // --- attention
  gemm_bt<1, 0, 0, 0><<<dim3(6, 16, 1), blk, 0, stream>>>(
      oute_bf, Wattn_bf, nullptr, key_bf, nullptr,
      2048, 768, 768, 768, 768, 768, 0, 0, 0, BIGR, 0);
  gemm_bt<0, 0, 0, 0><<<dim3(3, 2, 8), blk, 0, stream>>>(
      key_bf, enc_bf, nullptr, scores, nullptr,
      256, 257, 768, 768, 768, 288, 196608L, 294912L, 73728L, BIGR, 0);
  softmax_k<<<2048, blk, 0, stream>>>(scores, attn_bf);
  transpose_enc<<<dim3(9, 24, 8), blk, 0, stream>>>(enc_bf, encT_bf);
  gemm_bt<1, 0, 0, 0><<<dim3(6, 2, 8), blk, 0, stream>>>(
      attn_bf, encT_bf, nullptr, ctx_bf, nullptr,
      256, 768, 288, 288, 288, 768, 73728L, 221184L, 196608L, BIGR, 0);

  // --- feature concat + MLP + output projection
  feat_k<<<6144, blk, 0, stream>>>(oute_bf, ctx_bf, enc_bf, outw_bf,
                                   ki_bt, an_bt, feat_bf);
  gemm_bt<1, 0, 1, 1><<<dim3(6, 16, 1), blk, 0, stream>>>(
      feat_bf, Wmlp_bf, b_mlp, mlp_bf, nullptr,
      2040, 768, 3072, 3072, 3072, 768, 0, 0, 0, BIGR, 0);
  gemm_bt<0, 0, 0, 1><<<dim3(166, 16, 1), blk, 0, stream>>>(
      mlp_bf, Wout_bf, b_out, out, nullptr,
      2040, 21128, 768, 768, 768, 21128, 0, 0, 0, BIGR, 0);

  // --- log_softmax (in place) + hT/cT
  rowstat_k<<<2040, blk, 0, stream>>>(out, rowstat);
  finalize_k<<<42091, blk, 0, stream>>>(out, rowstat);
  tail_k<<<24, blk, 0, stream>>>(hstate, cstate, out);
}

// Round 2
// 4628.405 us; speedup vs baseline: 1.0377x; 1.0377x over previous
//
#include <hip/hip_runtime.h>
#include <hip/hip_bf16.h>

typedef short s16x8 __attribute__((ext_vector_type(8)));
typedef float f32x4 __attribute__((ext_vector_type(4)));
typedef unsigned short u16;
typedef unsigned short u16x4 __attribute__((ext_vector_type(4)));

__device__ __forceinline__ u16 f2bf(float f) {
  __hip_bfloat16 h = __float2bfloat16(f);
  u16 u;
  __builtin_memcpy(&u, &h, sizeof(u));
  return u;
}

// async global->LDS, 16B per lane; lds addr must be wave-uniform base
__device__ __forceinline__ void gload16(const void* g, void* l) {
  __builtin_amdgcn_global_load_lds(
      (const __attribute__((address_space(1))) unsigned int*)g,
      (__attribute__((address_space(3))) unsigned int*)l, 16, 0, 0);
}

// ---------------------------------------------------------------------------
// Generic bf16 MFMA GEMM:  C[m,n] = act( sum_k A[m,k]*B[n,k] + bias[n] )
// 128x128 tile, BK=32, 256 threads (4 waves, 2x2 wave grid, 4x4 16x16 frags).
// Staging via global_load_lds width-16 (linear LDS layout = lane order).
// Batched via blockIdx.z strides. C row remap: crow=(m/rpb)*cbs + (m%rpb)*ldc.
// Requirements: K%32==0; A rows allocated >= gridY*128 (per batch); B rows
// allocated >= gridX*128 (per batch). C writes masked to m<M, n<N.
// ---------------------------------------------------------------------------
template<int CBF16, int GATHER, int TANHA, int BIAS>
__global__ __launch_bounds__(256) void gemm_bt(
    const u16* __restrict__ A, const u16* __restrict__ B,
    const float* __restrict__ bias, void* __restrict__ Cv,
    const int* __restrict__ ids,
    int M, int N, int K, int lda, int ldb, int ldc,
    long sAz, long sBz, long sCz, int rpb, long cbs)
{
  __shared__ u16 sA[4096];
  __shared__ u16 sB[4096];
  const int tid = threadIdx.x;
  const int z = blockIdx.z;
  const int m0 = blockIdx.y * 128, n0 = blockIdx.x * 128;
  const u16* Ab = A + z * sAz;
  const u16* Bb = B + z * sBz;
  const int w = tid >> 6, lane = tid & 63;
  const int wr = w >> 1, wc = w & 1;
  const int lr = lane & 15, lk = lane >> 4;
  f32x4 acc[4][4] = {};
  const int e0 = tid * 8, e1 = e0 + 2048;
  const int r0 = e0 >> 5, c0 = e0 & 31;
  const int r1 = e1 >> 5, c1 = e1 & 31;
  long arow0, arow1;
  if (GATHER) {
    int i0 = m0 + r0; if (i0 >= M) i0 = M - 1;
    int i1 = m0 + r1; if (i1 >= M) i1 = M - 1;
    arow0 = (long)ids[i0] * lda;
    arow1 = (long)ids[i1] * lda;
  } else {
    arow0 = (long)(m0 + r0) * lda;
    arow1 = (long)(m0 + r1) * lda;
  }
  const long brow0 = (long)(n0 + r0) * ldb;
  const long brow1 = (long)(n0 + r1) * ldb;
  char* sAc = (char*)sA;
  char* sBc = (char*)sB;
  const size_t cb = (size_t)w * 1024;
  for (int kt = 0; kt < K; kt += 32) {
    __syncthreads();
    gload16(Ab + arow0 + kt + c0, sAc + cb);
    gload16(Ab + arow1 + kt + c1, sAc + 4096 + cb);
    gload16(Bb + brow0 + kt + c0, sBc + cb);
    gload16(Bb + brow1 + kt + c1, sBc + 4096 + cb);
    __syncthreads();
    s16x8 af[4], bf[4];
#pragma unroll
    for (int i = 0; i < 4; i++) {
      af[i] = *(const s16x8*)&sA[(wr*64 + i*16 + lr)*32 + lk*8];
      bf[i] = *(const s16x8*)&sB[(wc*64 + i*16 + lr)*32 + lk*8];
    }
#pragma unroll
    for (int mi = 0; mi < 4; mi++)
#pragma unroll
      for (int ni = 0; ni < 4; ni++)
        acc[mi][ni] = __builtin_amdgcn_mfma_f32_16x16x32_bf16(af[mi], bf[ni], acc[mi][ni], 0, 0, 0);
  }
#pragma unroll
  for (int mi = 0; mi < 4; mi++) {
#pragma unroll
    for (int ni = 0; ni < 4; ni++) {
#pragma unroll
      for (int r = 0; r < 4; r++) {
        int gm = m0 + wr*64 + mi*16 + lk*4 + r;
        int gn = n0 + wc*64 + ni*16 + lr;
        if (gm < M && gn < N) {
          float v = acc[mi][ni][r];
          if (BIAS) v += bias[gn];
          if (TANHA) v = tanhf(v);
          long ci = z * sCz + (long)(gm / rpb) * cbs + (long)(gm % rpb) * ldc + gn;
          if (CBF16) ((u16*)Cv)[ci] = f2bf(v);
          else       ((float*)Cv)[ci] = v;
        }
      }
    }
  }
}

// ---------------------------------------------------------------------------
// fp32 -> bf16 cast with zero padding beyond src rows/cols.
// ---------------------------------------------------------------------------
__global__ __launch_bounds__(256) void cast_pad(
    const float* __restrict__ src, u16* __restrict__ dst,
    int srows, int scols, int slda, int dcols)
{
  int r = blockIdx.y;
  int c = blockIdx.x * 256 + threadIdx.x;
  if (c >= dcols) return;
  float v = (r < srows && c < scols) ? src[(long)r * slda + c] : 0.f;
  dst[(long)r * dcols + c] = f2bf(v);
}

// init LSTM states (buf0): h for l=0,1 and c for l=0,1
__global__ __launch_bounds__(256) void init_k(
    const float* __restrict__ h0, const float* __restrict__ c0,
    float* __restrict__ hstate, float* __restrict__ cstate)
{
  int i = blockIdx.x * 256 + threadIdx.x;
  if (i < 6144) {
    hstate[i] = h0[i];
    hstate[6144 + i] = h0[i];
    cstate[i] = c0[i];
    cstate[6144 + i] = c0[i];
  }
}

// ---------------------------------------------------------------------------
// One LSTM timestep for both LSTMs. 768 WGs: wg -> (l, unit pair u0,u0+1).
// Wave w handles gate w for both units. Lane = (kq:3)(b:3): 96-deep partial
// dot, butterfly-reduce over kq. Gate combine + state update by first 16
// threads. h double-buffered across launches; W stays fp32 (L2-resident).
// ---------------------------------------------------------------------------
__global__ __launch_bounds__(256) void lstm_step2(
    const float* __restrict__ Whh_e, const float* __restrict__ Whh_w,
    const float* __restrict__ xW_e, const float* __restrict__ xW_w,
    const float* __restrict__ hsrc, float* __restrict__ hdst,
    float* __restrict__ cstate,
    u16* __restrict__ out_e, u16* __restrict__ out_w, int t)
{
  const int wg = blockIdx.x;
  const int l = (wg >= 384) ? 1 : 0;
  const int u0 = (wg - l * 384) * 2;
  const int tid = threadIdx.x;
  const int w = tid >> 6, lane = tid & 63;
  const int kq = lane >> 3, b = lane & 7;
  const float* W = (l ? Whh_w : Whh_e) + (long)(w * 768 + u0) * 768 + kq * 96;
  const float* hp = hsrc + l * 6144 + b * 768 + kq * 96;
  float a0 = 0.f, a1 = 0.f;
#pragma unroll 8
  for (int k = 0; k < 96; k += 4) {
    float4 hv = *(const float4*)(hp + k);
    float4 x0 = *(const float4*)(W + k);
    float4 x1 = *(const float4*)(W + 768 + k);
    a0 += x0.x*hv.x + x0.y*hv.y + x0.z*hv.z + x0.w*hv.w;
    a1 += x1.x*hv.x + x1.y*hv.y + x1.z*hv.z + x1.w*hv.w;
  }
#pragma unroll
  for (int off = 8; off < 64; off <<= 1) {
    a0 += __shfl_xor(a0, off);
    a1 += __shfl_xor(a1, off);
  }
  __shared__ float g4[4][2][8];
  if (lane < 8) g4[w][0][b] = a0;
  else if (lane < 16) g4[w][1][b] = a1;
  __syncthreads();
  if (tid < 16) {
    const int ui = tid >> 3, bb = tid & 7;
    const int u = u0 + ui;
    float gi = g4[0][ui][bb], gf = g4[1][ui][bb];
    float gg = g4[2][ui][bb], go = g4[3][ui][bb];
    const float* xr = l ? (xW_w + ((long)bb * 257 + t) * 3072)
                        : (xW_e + ((long)bb * 256 + t) * 3072);
    gi += xr[u]; gf += xr[768 + u]; gg += xr[1536 + u]; go += xr[2304 + u];
    float si = 1.f / (1.f + expf(-gi));
    float sf = 1.f / (1.f + expf(-gf));
    float so = 1.f / (1.f + expf(-go));
    const int ci = l * 6144 + bb * 768 + u;
    float c2 = sf * cstate[ci] + si * tanhf(gg);
    float h2 = so * tanhf(c2);
    cstate[ci] = c2;
    hdst[ci] = h2;
    (l ? out_w : out_e)[((long)bb * 256 + t) * 768 + u] = f2bf(h2);
  }
}

// counter recurrence: 8 lanes scan 255 steps (pre-update ki/an recorded)
__global__ void counters_k(const int* __restrict__ input_edits,
                           const int* __restrict__ org_ids,
                           int* __restrict__ ki_bt, int* __restrict__ an_bt)
{
  int b = threadIdx.x;
  if (b >= 8) return;
  int kd = 0, ki = 0, an = 0;
  for (int t = 0; t < 255; t++) {
    int a = input_edits[b * 256 + t + 1];
    ki_bt[b * 255 + t] = ki;
    an_bt[b * 255 + t] = an;
    int kd2 = kd + ((a == 1) || (a == 2) ? 1 : 0);
    int ns = (a != 2) && (a != 102) && (a != 0);
    int ki2 = ki + (ns ? 1 : 0);
    int is_ins = ns && (a != 1);
    int nia = (org_ids[b * 257 + an + 1] == 103);
    int mx = (kd2 > an) ? kd2 : an;
    int an2 = (is_ins && nia) ? (an + 1) : mx;
    kd = kd2; ki = ki2; an = an2;
  }
}

// softmax over s (257 valid of 288) per (b,t) row; writes bf16 attn, zero pad
__global__ __launch_bounds__(256) void softmax_k(
    const float* __restrict__ scores, u16* __restrict__ attn)
{
  const int row = blockIdx.x;                 // 0..2047
  const float* src = scores + (long)row * 288;
  u16* dst = attn + (long)row * 288;
  const int tid = threadIdx.x;
  float v0 = (tid < 257) ? src[tid] : -1e30f;
  float v1 = (tid + 256 < 257) ? src[tid + 256] : -1e30f;
  float mx = fmaxf(v0, v1);
  for (int o = 32; o; o >>= 1) mx = fmaxf(mx, __shfl_xor(mx, o));
  __shared__ float sm[4];
  __shared__ float ss[4];
  if ((tid & 63) == 0) sm[tid >> 6] = mx;
  __syncthreads();
  mx = fmaxf(fmaxf(sm[0], sm[1]), fmaxf(sm[2], sm[3]));
  float e0 = (tid < 257) ? expf(v0 - mx) : 0.f;
  float e1 = (tid + 256 < 257) ? expf(v1 - mx) : 0.f;
  float s = e0 + e1;
  for (int o = 32; o; o >>= 1) s += __shfl_xor(s, o);
  if ((tid & 63) == 0) ss[tid >> 6] = s;
  __syncthreads();
  s = ss[0] + ss[1] + ss[2] + ss[3];
  float inv = 1.f / s;
  dst[tid] = f2bf(e0 * inv);
  if (tid + 256 < 288) dst[tid + 256] = f2bf(e1 * inv);
}

// enc_bf [8][384][768] -> encT_bf [8][768][288] (zero pad s>=257)
__global__ __launch_bounds__(256) void transpose_enc(
    const u16* __restrict__ enc, u16* __restrict__ encT)
{
  __shared__ u16 tile[32][33];
  const int b = blockIdx.z, h0 = blockIdx.y * 32, s0 = blockIdx.x * 32;
  const int tx = threadIdx.x & 31, ty = threadIdx.x >> 5;  // ty 0..7
#pragma unroll
  for (int i = 0; i < 32; i += 8) {
    int s = s0 + ty + i;
    u16 v = (s < 257) ? enc[((long)b * 384 + s) * 768 + h0 + tx] : (u16)0;
    tile[ty + i][tx] = v;
  }
  __syncthreads();
#pragma unroll
  for (int i = 0; i < 32; i += 8) {
    int h = h0 + ty + i;
    encT[((long)b * 768 + h) * 288 + s0 + tx] = tile[tx][ty + i];
  }
}

// feat[2048][3072] bf16 = [out_edits | ctx | enc(an) | out_words(ki)], 0-pad
__global__ __launch_bounds__(256) void feat_k(
    const u16* __restrict__ oute, const u16* __restrict__ ctx,
    const u16* __restrict__ encb, const u16* __restrict__ outw,
    const int* __restrict__ ki_bt, const int* __restrict__ an_bt,
    u16* __restrict__ feat)
{
  int q = blockIdx.x * 256 + threadIdx.x;       // < 1572864 (u16x4 units)
  int m = q / 768, qq = q - m * 768;
  int seg = qq / 192, off = (qq - seg * 192) * 4;
  u16x4 v = {0, 0, 0, 0};
  if (m < 2040) {
    int b = m / 255, t = m - b * 255;
    const u16* src;
    if (seg == 0)      src = oute + ((long)(b * 256 + t)) * 768 + off;
    else if (seg == 1) src = ctx  + ((long)(b * 256 + t)) * 768 + off;
    else if (seg == 2) src = encb + ((long)(b * 384 + an_bt[m])) * 768 + off;
    else               src = outw + ((long)(b * 256 + ki_bt[m])) * 768 + off;
    v = *(const u16x4*)src;
  }
  *(u16x4*)(feat + (long)q * 4) = v;
}

// online max/sum-exp per logits row -> rowstat = max + log(sumexp)
__global__ __launch_bounds__(256) void rowstat_k(
    const float* __restrict__ logits, float* __restrict__ rowstat)
{
  const int m = blockIdx.x;
  const float* row = logits + (long)m * 21128;
  const int tid = threadIdx.x;
  float mx = -1e30f, sm = 0.f;
  for (int i = tid * 4; i < 21128; i += 1024) {
    float4 v = *(const float4*)(row + i);
    float m4 = fmaxf(fmaxf(v.x, v.y), fmaxf(v.z, v.w));
    if (m4 > mx) { sm *= expf(mx - m4); mx = m4; }
    sm += expf(v.x - mx) + expf(v.y - mx) + expf(v.z - mx) + expf(v.w - mx);
  }
  for (int o = 32; o; o >>= 1) {
    float mo = __shfl_xor(mx, o), so = __shfl_xor(sm, o);
    float nm = fmaxf(mx, mo);
    sm = sm * expf(mx - nm) + so * expf(mo - nm);
    mx = nm;
  }
  __shared__ float wm[4], wsum[4];
  if ((tid & 63) == 0) { wm[tid >> 6] = mx; wsum[tid >> 6] = sm; }
  __syncthreads();
  if (tid == 0) {
    float M = wm[0], S = wsum[0];
    for (int i = 1; i < 4; i++) {
      float nm = fmaxf(M, wm[i]);
      S = S * expf(M - nm) + wsum[i] * expf(wm[i] - nm);
      M = nm;
    }
    rowstat[m] = M + logf(S);
  }
}

// in-place logp = logit - rowstat[row]
__global__ __launch_bounds__(256) void finalize_k(
    float* __restrict__ logits, const float* __restrict__ rowstat)
{
  long i4 = (long)blockIdx.x * 256 + threadIdx.x;
  if (i4 >= 10775280L) return;
  long i = i4 * 4;
  int m = (int)(i / 21128);
  float rs = rowstat[m];
  float4* p = (float4*)(logits + i);
  float4 v = *p;
  v.x -= rs; v.y -= rs; v.z -= rs; v.w -= rs;
  *p = v;
}

// copy hT (edits h state, buf0 l=0) and cT into d_out tail
__global__ __launch_bounds__(256) void tail_k(
    const float* __restrict__ hstate, const float* __restrict__ cstate,
    float* __restrict__ out)
{
  int i = blockIdx.x * 256 + threadIdx.x;
  if (i < 6144) {
    out[43101120 + i] = hstate[i];
    out[43107264 + i] = cstate[i];
  }
}

// ---------------------------------------------------------------------------
extern "C" void kernel_launch(void* const* d_in, const int* in_sizes, int n_in,
                              void* d_out, int out_size, void* d_ws, size_t ws_size,
                              hipStream_t stream) {
  (void)in_sizes; (void)n_in; (void)out_size; (void)ws_size;
  const int*   input_edits = (const int*)d_in[0];
  const int*   org_ids     = (const int*)d_in[1];
  const int*   simp_sent   = (const int*)d_in[2];
  const float* h0      = (const float*)d_in[3];
  const float* c0      = (const float*)d_in[4];
  const float* encoder = (const float*)d_in[5];
  const float* emb     = (const float*)d_in[6];
  const float* Wih_e   = (const float*)d_in[7];
  const float* Whh_e   = (const float*)d_in[8];
  const float* b_e     = (const float*)d_in[9];
  const float* Wih_w   = (const float*)d_in[10];
  const float* Whh_w   = (const float*)d_in[11];
  const float* b_w     = (const float*)d_in[12];
  const float* W_attn  = (const float*)d_in[13];
  const float* W_align = (const float*)d_in[14];
  const float* W_mlp   = (const float*)d_in[15];
  const float* b_mlp   = (const float*)d_in[16];
  const float* W_out   = (const float*)d_in[17];
  const float* b_out   = (const float*)d_in[18];

  float* out = (float*)d_out;
  // --- d_out region doubles as scratch until the logits GEMM overwrites it
  float* xW_e = out;                               // [2048][3072] f32
  float* xW_w = out + 2048L * 3072;                // [2056][3072] f32
  u16* emb_bf  = (u16*)(out + 2048L * 3072 + 2056L * 3072);  // [21128][768]
  u16* encd_bf = emb_bf + 21128L * 768;            // [2176][768] (pad rows 0)
  u16* feat_bf = encd_bf + 2176L * 768;            // [2048][3072]

  // --- ws scratch (~77 MB high-water)
  char* p = (char*)d_ws;
  auto alloc = [&](size_t bytes) -> char* {
    char* r = p; p += (bytes + 255) & ~(size_t)255; return r;
  };
  u16* Wout_bf   = (u16*)alloc(21248L * 768 * 2);
  u16* Wihe_bf   = (u16*)alloc(3072L * 768 * 2);
  u16* Wihw_bf   = (u16*)alloc(3072L * 768 * 2);
  u16* Wmlp_bf   = (u16*)alloc(768L * 3072 * 2);
  u16* Walign_bf = (u16*)alloc(768L * 768 * 2);
  u16* Wattn_bf  = (u16*)alloc(768L * 768 * 2);
  u16* enc_bf    = (u16*)alloc(8L * 384 * 768 * 2);   // padded batch stride
  u16* encT_bf   = (u16*)alloc(8L * 768 * 288 * 2);   // K padded to 288
  u16* oute_bf   = (u16*)alloc(2048L * 768 * 2);
  u16* outw_bf   = (u16*)alloc(2048L * 768 * 2);
  u16* key_bf    = (u16*)alloc(2048L * 768 * 2);
  u16* attn_bf   = (u16*)alloc(8L * 256 * 288 * 2);
  u16* ctx_bf    = (u16*)alloc(2048L * 768 * 2);
  u16* mlp_bf    = (u16*)alloc(2048L * 768 * 2);
  float* scores  = (float*)alloc(8L * 256 * 288 * 4);
  float* hstate  = (float*)alloc(2L * 2 * 6144 * 4);  // [buf][l][6144]
  float* cstate  = (float*)alloc(2L * 6144 * 4);      // [l][6144]
  int* ki_bt     = (int*)alloc(2040 * 4);
  int* an_bt     = (int*)alloc(2040 * 4);
  float* rowstat = (float*)alloc(2048 * 4);

  dim3 blk(256);
  const int BIGR = 1 << 30;

  // --- casts (fp32 -> bf16, with padding)
  cast_pad<<<dim3(3, 21128), blk, 0, stream>>>(emb, emb_bf, 21128, 768, 768, 768);
  cast_pad<<<dim3(3, 21248), blk, 0, stream>>>(W_out, Wout_bf, 21128, 768, 768, 768);
  cast_pad<<<dim3(3, 3072), blk, 0, stream>>>(Wih_e, Wihe_bf, 3072, 768, 768, 768);
  cast_pad<<<dim3(3, 3072), blk, 0, stream>>>(Wih_w, Wihw_bf, 3072, 768, 768, 768);
  cast_pad<<<dim3(12, 768), blk, 0, stream>>>(W_mlp, Wmlp_bf, 768, 3072, 3072, 3072);
  cast_pad<<<dim3(3, 768), blk, 0, stream>>>(W_align, Walign_bf, 768, 768, 768, 768);
  cast_pad<<<dim3(3, 768), blk, 0, stream>>>(W_attn, Wattn_bf, 768, 768, 768, 768);
  cast_pad<<<dim3(3, 2176), blk, 0, stream>>>(encoder, encd_bf, 2056, 768, 768, 768);
  init_k<<<24, blk, 0, stream>>>(h0, c0, hstate, cstate);
  counters_k<<<1, 64, 0, stream>>>(input_edits, org_ids, ki_bt, an_bt);

  // --- enc = tanh(encoder @ W_align^T) -> bf16, padded [8][384][768] layout
  gemm_bt<1, 0, 1, 0><<<dim3(6, 17, 1), blk, 0, stream>>>(
      encd_bf, Walign_bf, nullptr, enc_bf, nullptr,
      2056, 768, 768, 768, 768, 768, 0, 0, 0, 257, 294912L);

  // --- hoisted LSTM input projections (embedding gather + bias)
  gemm_bt<0, 1, 0, 1><<<dim3(24, 16, 1), blk, 0, stream>>>(
      emb_bf, Wihe_bf, b_e, xW_e, input_edits,
      2048, 3072, 768, 768, 768, 3072, 0, 0, 0, BIGR, 0);
  gemm_bt<0, 1, 0, 1><<<dim3(24, 17, 1), blk, 0, stream>>>(
      emb_bf, Wihw_bf, b_w, xW_w, simp_sent,
      2056, 3072, 768, 768, 768, 3072, 0, 0, 0, BIGR, 0);

  // --- sequential recurrences, both LSTMs per launch
  for (int t = 0; t < 256; t++) {
    lstm_step2<<<dim3(768), blk, 0, stream>>>(
        Whh_e, Whh_w, xW_e, xW_w,
        hstate + (t & 1) * 12288, hstate + ((t + 1) & 1) * 12288,
        cstate, oute_bf, outw_bf, t);
  }

  // --- attention
  gemm_bt<1, 0, 0, 0><<<dim3(6, 16, 1), blk, 0, stream>>>(
      oute_bf, Wattn_bf, nullptr, key_bf, nullptr,
      2048, 768, 768, 768, 768, 768, 0, 0, 0, BIGR, 0);
  gemm_bt<0, 0, 0, 0><<<dim3(3, 2, 8), blk, 0, stream>>>(
      key_bf, enc_bf, nullptr, scores, nullptr,
      256, 257, 768, 768, 768, 288, 196608L, 294912L, 73728L, BIGR, 0);
  softmax_k<<<2048, blk, 0, stream>>>(scores, attn_bf);
  transpose_enc<<<dim3(9, 24, 8), blk, 0, stream>>>(enc_bf, encT_bf);
  gemm_bt<1, 0, 0, 0><<<dim3(6, 2, 8), blk, 0, stream>>>(
      attn_bf, encT_bf, nullptr, ctx_bf, nullptr,
      256, 768, 288, 288, 288, 768, 73728L, 221184L, 196608L, BIGR, 0);

  // --- feature concat + MLP + output projection
  feat_k<<<6144, blk, 0, stream>>>(oute_bf, ctx_bf, enc_bf, outw_bf,
                                   ki_bt, an_bt, feat_bf);
  gemm_bt<1, 0, 1, 1><<<dim3(6, 16, 1), blk, 0, stream>>>(
      feat_bf, Wmlp_bf, b_mlp, mlp_bf, nullptr,
      2040, 768, 3072, 3072, 3072, 768, 0, 0, 0, BIGR, 0);
  gemm_bt<0, 0, 0, 1><<<dim3(166, 16, 1), blk, 0, stream>>>(
      mlp_bf, Wout_bf, b_out, out, nullptr,
      2040, 21128, 768, 768, 768, 21128, 0, 0, 0, BIGR, 0);

  // --- log_softmax (in place) + hT/cT
  rowstat_k<<<2040, blk, 0, stream>>>(out, rowstat);
  finalize_k<<<42091, blk, 0, stream>>>(out, rowstat);
  tail_k<<<24, blk, 0, stream>>>(hstate, cstate, out);
}

// Round 3
// 3235.213 us; speedup vs baseline: 1.4845x; 1.4306x over previous
//
#include <hip/hip_runtime.h>
#include <hip/hip_bf16.h>

typedef short s16x8 __attribute__((ext_vector_type(8)));
typedef float f32x4 __attribute__((ext_vector_type(4)));
typedef unsigned short u16;
typedef unsigned short u16x4 __attribute__((ext_vector_type(4)));

__device__ __forceinline__ u16 f2bf(float f) {
  __hip_bfloat16 h = __float2bfloat16(f);
  u16 u;
  __builtin_memcpy(&u, &h, sizeof(u));
  return u;
}
__device__ __forceinline__ float bf2f(u16 u) {
  unsigned int x = ((unsigned int)u) << 16;
  float f;
  __builtin_memcpy(&f, &x, 4);
  return f;
}

// async global->LDS, 16B per lane; lds addr must be wave-uniform base
__device__ __forceinline__ void gload16(const void* g, void* l) {
  __builtin_amdgcn_global_load_lds(
      (const __attribute__((address_space(1))) unsigned int*)g,
      (__attribute__((address_space(3))) unsigned int*)l, 16, 0, 0);
}

// ---------------------------------------------------------------------------
// Generic bf16 MFMA GEMM:  C[m,n] = act( sum_k A[m,k]*B[n,k] + bias[n] )
// 128x128 tile, BK=32, 256 threads. Staging via global_load_lds width-16.
// ---------------------------------------------------------------------------
template<int CBF16, int GATHER, int TANHA, int BIAS>
__global__ __launch_bounds__(256) void gemm_bt(
    const u16* __restrict__ A, const u16* __restrict__ B,
    const float* __restrict__ bias, void* __restrict__ Cv,
    const int* __restrict__ ids,
    int M, int N, int K, int lda, int ldb, int ldc,
    long sAz, long sBz, long sCz, int rpb, long cbs)
{
  __shared__ u16 sA[4096];
  __shared__ u16 sB[4096];
  const int tid = threadIdx.x;
  const int z = blockIdx.z;
  const int m0 = blockIdx.y * 128, n0 = blockIdx.x * 128;
  const u16* Ab = A + z * sAz;
  const u16* Bb = B + z * sBz;
  const int w = tid >> 6, lane = tid & 63;
  const int wr = w >> 1, wc = w & 1;
  const int lr = lane & 15, lk = lane >> 4;
  f32x4 acc[4][4] = {};
  const int e0 = tid * 8, e1 = e0 + 2048;
  const int r0 = e0 >> 5, c0 = e0 & 31;
  const int r1 = e1 >> 5, c1 = e1 & 31;
  long arow0, arow1;
  if (GATHER) {
    int i0 = m0 + r0; if (i0 >= M) i0 = M - 1;
    int i1 = m0 + r1; if (i1 >= M) i1 = M - 1;
    arow0 = (long)ids[i0] * lda;
    arow1 = (long)ids[i1] * lda;
  } else {
    arow0 = (long)(m0 + r0) * lda;
    arow1 = (long)(m0 + r1) * lda;
  }
  const long brow0 = (long)(n0 + r0) * ldb;
  const long brow1 = (long)(n0 + r1) * ldb;
  char* sAc = (char*)sA;
  char* sBc = (char*)sB;
  const size_t cb = (size_t)w * 1024;
  for (int kt = 0; kt < K; kt += 32) {
    __syncthreads();
    gload16(Ab + arow0 + kt + c0, sAc + cb);
    gload16(Ab + arow1 + kt + c1, sAc + 4096 + cb);
    gload16(Bb + brow0 + kt + c0, sBc + cb);
    gload16(Bb + brow1 + kt + c1, sBc + 4096 + cb);
    __syncthreads();
    s16x8 af[4], bf[4];
#pragma unroll
    for (int i = 0; i < 4; i++) {
      af[i] = *(const s16x8*)&sA[(wr*64 + i*16 + lr)*32 + lk*8];
      bf[i] = *(const s16x8*)&sB[(wc*64 + i*16 + lr)*32 + lk*8];
    }
#pragma unroll
    for (int mi = 0; mi < 4; mi++)
#pragma unroll
      for (int ni = 0; ni < 4; ni++)
        acc[mi][ni] = __builtin_amdgcn_mfma_f32_16x16x32_bf16(af[mi], bf[ni], acc[mi][ni], 0, 0, 0);
  }
#pragma unroll
  for (int mi = 0; mi < 4; mi++) {
#pragma unroll
    for (int ni = 0; ni < 4; ni++) {
#pragma unroll
      for (int r = 0; r < 4; r++) {
        int gm = m0 + wr*64 + mi*16 + lk*4 + r;
        int gn = n0 + wc*64 + ni*16 + lr;
        if (gm < M && gn < N) {
          float v = acc[mi][ni][r];
          if (BIAS) v += bias[gn];
          if (TANHA) v = tanhf(v);
          long ci = z * sCz + (long)(gm / rpb) * cbs + (long)(gm % rpb) * ldc + gn;
          if (CBF16) ((u16*)Cv)[ci] = f2bf(v);
          else       ((float*)Cv)[ci] = v;
        }
      }
    }
  }
}

// ---------------------------------------------------------------------------
// All fp32->bf16 casts in one dispatch. One block per destination row.
// ---------------------------------------------------------------------------
__global__ __launch_bounds__(256) void cast_all(
    const float* __restrict__ emb, u16* __restrict__ emb_bf,
    const float* __restrict__ Wout, u16* __restrict__ Wout_bf,
    const float* __restrict__ Wihe, u16* __restrict__ Wihe_bf,
    const float* __restrict__ Wihw, u16* __restrict__ Wihw_bf,
    const float* __restrict__ Wmlp, u16* __restrict__ Wmlp_bf,
    const float* __restrict__ Walign, u16* __restrict__ Walign_bf,
    const float* __restrict__ Wattn, u16* __restrict__ Wattn_bf,
    const float* __restrict__ encoder, u16* __restrict__ encd_bf)
{
  int r = blockIdx.x;
  const float* src; u16* dst; int srows, cols;
  if (r < 21128)                    { src=emb;    dst=emb_bf;    srows=21128; cols=768; }
  else if ((r -= 21128) < 21248)    { src=Wout;   dst=Wout_bf;   srows=21128; cols=768; }
  else if ((r -= 21248) < 3072)     { src=Wihe;   dst=Wihe_bf;   srows=3072;  cols=768; }
  else if ((r -= 3072) < 3072)      { src=Wihw;   dst=Wihw_bf;   srows=3072;  cols=768; }
  else if ((r -= 3072) < 768)       { src=Wmlp;   dst=Wmlp_bf;   srows=768;   cols=3072; }
  else if ((r -= 768) < 768)        { src=Walign; dst=Walign_bf; srows=768;   cols=768; }
  else if ((r -= 768) < 768)        { src=Wattn;  dst=Wattn_bf;  srows=768;   cols=768; }
  else { r -= 768;                    src=encoder; dst=encd_bf;  srows=2056;  cols=768; }
  for (int c = threadIdx.x; c < cols; c += 256) {
    float v = (r < srows) ? src[(long)r * cols + c] : 0.f;
    dst[(long)r * cols + c] = f2bf(v);
  }
}

// counter recurrence (8 lanes) + zero the persistent-kernel barrier counters
__global__ void counters_k(const int* __restrict__ input_edits,
                           const int* __restrict__ org_ids,
                           int* __restrict__ ki_bt, int* __restrict__ an_bt,
                           unsigned int* __restrict__ ctr)
{
  int b = threadIdx.x;
  if (b == 8) { ctr[0] = 0; ctr[1] = 0; }
  if (b >= 8) return;
  int kd = 0, ki = 0, an = 0;
  for (int t = 0; t < 255; t++) {
    int a = input_edits[b * 256 + t + 1];
    ki_bt[b * 255 + t] = ki;
    an_bt[b * 255 + t] = an;
    int kd2 = kd + ((a == 1) || (a == 2) ? 1 : 0);
    int ns = (a != 2) && (a != 102) && (a != 0);
    int ki2 = ki + (ns ? 1 : 0);
    int is_ins = ns && (a != 1);
    int nia = (org_ids[b * 257 + an + 1] == 103);
    int mx = (kd2 > an) ? kd2 : an;
    int an2 = (is_ins && nia) ? (an + 1) : mx;
    kd = kd2; ki = ki2; an = an2;
  }
}

// device-scope group barrier (monotonic counter, zeroed by counters_k)
__device__ __forceinline__ void grp_barrier(unsigned int* c, unsigned int target) {
  __syncthreads();
  if (threadIdx.x == 0) {
    __threadfence();
    __hip_atomic_fetch_add(c, 1u, __ATOMIC_ACQ_REL, __HIP_MEMORY_SCOPE_AGENT);
    while (__hip_atomic_load(c, __ATOMIC_ACQUIRE, __HIP_MEMORY_SCOPE_AGENT) < target)
      __builtin_amdgcn_s_sleep(1);
    __threadfence();
  }
  __syncthreads();
}

// ---------------------------------------------------------------------------
// Persistent LSTM: 96 WGs = 2 LSTMs x 48 groups (16 units each). W held in
// VGPRs as MFMA B-frags (24 slabs). h as split bf16 (hi+lo) in swizzled
// global buffer, double-buffered per step; staged via global_load_lds.
// 128 updater threads do gates/nonlin; c-state in VGPRs. Spin barrier/step.
// ---------------------------------------------------------------------------
__global__ __launch_bounds__(256, 1) void lstm_persist(
    const float* __restrict__ Whh_e, const float* __restrict__ Whh_w,
    const float* __restrict__ xW_e, const float* __restrict__ xW_w,
    const float* __restrict__ h0, const float* __restrict__ c0,
    u16* __restrict__ hglob, unsigned int* __restrict__ ctr,
    u16* __restrict__ out_e, u16* __restrict__ out_w,
    float* __restrict__ out_tail)
{
  const int wg = blockIdx.x;
  const int l = wg / 48, grp = wg % 48;
  const int u0 = grp * 16;
  const int tid = threadIdx.x;
  const int w = tid >> 6, lane = tid & 63;
  const int c16 = lane & 15, half = lane >> 4;

  __shared__ u16 ldsh[24576];       // [part2][16][768] bf16 (48 KB)
  __shared__ float G[8][64];        // raw gate values

  // ---- W fragments (persistent in VGPRs). B-frag: lane holds
  // W[row = gate*768 + u0 + ul][s*32 + half*8 .. +8], row from (w,c16) map.
  const int gate = c16 & 3, ul = w * 4 + (c16 >> 2);
  const int wrow = gate * 768 + u0 + ul;
  const float* Wsrc = (l ? Whh_w : Whh_e) + (long)wrow * 768 + half * 8;
  s16x8 wfrag[24];
#pragma unroll
  for (int s = 0; s < 24; s++) {
    float4 f0 = *(const float4*)(Wsrc + s * 32);
    float4 f1 = *(const float4*)(Wsrc + s * 32 + 4);
    s16x8 v;
    v[0]=f2bf(f0.x); v[1]=f2bf(f0.y); v[2]=f2bf(f0.z); v[3]=f2bf(f0.w);
    v[4]=f2bf(f1.x); v[5]=f2bf(f1.y); v[6]=f2bf(f1.z); v[7]=f2bf(f1.w);
    wfrag[s] = v;
  }

  // ---- updater identity + c-state
  const int ub = tid >> 4, uu = tid & 15;        // valid for tid<128
  const int ug = u0 + uu;
  float creg = (tid < 128) ? c0[ub * 768 + ug] : 0.f;

  u16* hg = hglob + l * 49152;                   // [buf2][part2][16][768]
  // ---- h0 init (group leader WG writes rows 0..7, split hi/lo, swizzled)
  if (grp == 0) {
    for (int i = tid; i < 6144; i += 256) {
      int b = i / 768, u = i - b * 768;
      float v = h0[i];
      u16 hi = f2bf(v);
      u16 lo = f2bf(v - bf2f(hi));
      int swi = b * 768 + ((((u >> 3) ^ (b & 7))) << 3) + (u & 7);
      hg[swi] = hi;
      hg[12288 + swi] = lo;
    }
  }
  grp_barrier(ctr + l, 48u);

  const float* xWl = l ? xW_w : xW_e;
  const int trow = l ? 257 : 256;

  for (int t = 0; t < 256; t++) {
    // stage h buf (t&1) -> LDS, linear 48 KB
    const u16* hsrc = hg + (t & 1) * 24576;
    {
      char* lb = (char*)ldsh;
#pragma unroll
      for (int i = 0; i < 12; i++)
        gload16(hsrc + (i * 256 + tid) * 8, lb + (i * 256 + w * 64) * 16);
    }
    __syncthreads();

    f32x4 acc = {};
#pragma unroll
    for (int s = 0; s < 24; s++) {
      const int soff = (((s * 4 + half) ^ (c16 & 7)) << 3);
      s16x8 ahi = *(const s16x8*)&ldsh[c16 * 768 + soff];
      s16x8 alo = *(const s16x8*)&ldsh[12288 + c16 * 768 + soff];
      acc = __builtin_amdgcn_mfma_f32_16x16x32_bf16(ahi, wfrag[s], acc, 0, 0, 0);
      acc = __builtin_amdgcn_mfma_f32_16x16x32_bf16(alo, wfrag[s], acc, 0, 0, 0);
    }
    if (half < 2) {
#pragma unroll
      for (int r = 0; r < 4; r++)
        G[half * 4 + r][w * 16 + c16] = acc[r];
    }
    __syncthreads();

    if (tid < 128) {
      const float* xr = xWl + ((long)ub * trow + t) * 3072;
      const int cb = (uu >> 2) * 16 + (uu & 3) * 4;
      float gi = G[ub][cb + 0] + xr[ug];
      float gf = G[ub][cb + 1] + xr[768 + ug];
      float gg = G[ub][cb + 2] + xr[1536 + ug];
      float go = G[ub][cb + 3] + xr[2304 + ug];
      float si = 1.f / (1.f + expf(-gi));
      float sf = 1.f / (1.f + expf(-gf));
      float so = 1.f / (1.f + expf(-go));
      float c2 = sf * creg + si * tanhf(gg);
      float h2 = so * tanhf(c2);
      creg = c2;
      u16 hi = f2bf(h2);
      u16 lo = f2bf(h2 - bf2f(hi));
      const int swi = ub * 768 + (((ug >> 3) ^ (ub & 7)) << 3) + (ug & 7);
      u16* hb = hg + ((t + 1) & 1) * 24576;
      hb[swi] = hi;
      hb[12288 + swi] = lo;
      (l ? out_w : out_e)[((long)ub * 256 + t) * 768 + ug] = hi;
      if (l == 0 && t == 255) {
        out_tail[43101120 + ub * 768 + ug] = h2;
        out_tail[43107264 + ub * 768 + ug] = c2;
      }
    }
    grp_barrier(ctr + l, 48u * (t + 2));
  }
}

// softmax over s (257 valid of 288) per (b,t) row; writes bf16 attn, zero pad
__global__ __launch_bounds__(256) void softmax_k(
    const float* __restrict__ scores, u16* __restrict__ attn)
{
  const int row = blockIdx.x;                 // 0..2047
  const float* src = scores + (long)row * 288;
  u16* dst = attn + (long)row * 288;
  const int tid = threadIdx.x;
  float v0 = (tid < 257) ? src[tid] : -1e30f;
  float v1 = (tid + 256 < 257) ? src[tid + 256] : -1e30f;
  float mx = fmaxf(v0, v1);
  for (int o = 32; o; o >>= 1) mx = fmaxf(mx, __shfl_xor(mx, o));
  __shared__ float sm[4];
  __shared__ float ss[4];
  if ((tid & 63) == 0) sm[tid >> 6] = mx;
  __syncthreads();
  mx = fmaxf(fmaxf(sm[0], sm[1]), fmaxf(sm[2], sm[3]));
  float e0 = (tid < 257) ? expf(v0 - mx) : 0.f;
  float e1 = (tid + 256 < 257) ? expf(v1 - mx) : 0.f;
  float s = e0 + e1;
  for (int o = 32; o; o >>= 1) s += __shfl_xor(s, o);
  if ((tid & 63) == 0) ss[tid >> 6] = s;
  __syncthreads();
  s = ss[0] + ss[1] + ss[2] + ss[3];
  float inv = 1.f / s;
  dst[tid] = f2bf(e0 * inv);
  if (tid + 256 < 288) dst[tid + 256] = f2bf(e1 * inv);
}

// enc_bf [8][384][768] -> encT_bf [8][768][288] (zero pad s>=257)
__global__ __launch_bounds__(256) void transpose_enc(
    const u16* __restrict__ enc, u16* __restrict__ encT)
{
  __shared__ u16 tile[32][33];
  const int b = blockIdx.z, h0 = blockIdx.y * 32, s0 = blockIdx.x * 32;
  const int tx = threadIdx.x & 31, ty = threadIdx.x >> 5;  // ty 0..7
#pragma unroll
  for (int i = 0; i < 32; i += 8) {
    int s = s0 + ty + i;
    u16 v = (s < 257) ? enc[((long)b * 384 + s) * 768 + h0 + tx] : (u16)0;
    tile[ty + i][tx] = v;
  }
  __syncthreads();
#pragma unroll
  for (int i = 0; i < 32; i += 8) {
    int h = h0 + ty + i;
    encT[((long)b * 768 + h) * 288 + s0 + tx] = tile[tx][ty + i];
  }
}

// feat[2048][3072] bf16 = [out_edits | ctx | enc(an) | out_words(ki)], 0-pad
__global__ __launch_bounds__(256) void feat_k(
    const u16* __restrict__ oute, const u16* __restrict__ ctx,
    const u16* __restrict__ encb, const u16* __restrict__ outw,
    const int* __restrict__ ki_bt, const int* __restrict__ an_bt,
    u16* __restrict__ feat)
{
  int q = blockIdx.x * 256 + threadIdx.x;       // < 1572864 (u16x4 units)
  int m = q / 768, qq = q - m * 768;
  int seg = qq / 192, off = (qq - seg * 192) * 4;
  u16x4 v = {0, 0, 0, 0};
  if (m < 2040) {
    int b = m / 255, t = m - b * 255;
    const u16* src;
    if (seg == 0)      src = oute + ((long)(b * 256 + t)) * 768 + off;
    else if (seg == 1) src = ctx  + ((long)(b * 256 + t)) * 768 + off;
    else if (seg == 2) src = encb + ((long)(b * 384 + an_bt[m])) * 768 + off;
    else               src = outw + ((long)(b * 256 + ki_bt[m])) * 768 + off;
    v = *(const u16x4*)src;
  }
  *(u16x4*)(feat + (long)q * 4) = v;
}

// fused log_softmax: per-row stat then in-place subtract (row stays in L2)
__global__ __launch_bounds__(256) void logsoftmax_k(float* __restrict__ logits)
{
  const int m = blockIdx.x;
  float* row = logits + (long)m * 21128;
  const int tid = threadIdx.x;
  float mx = -1e30f, sm = 0.f;
  for (int i = tid * 4; i < 21128; i += 1024) {
    float4 v = *(const float4*)(row + i);
    float m4 = fmaxf(fmaxf(v.x, v.y), fmaxf(v.z, v.w));
    if (m4 > mx) { sm *= expf(mx - m4); mx = m4; }
    sm += expf(v.x - mx) + expf(v.y - mx) + expf(v.z - mx) + expf(v.w - mx);
  }
  for (int o = 32; o; o >>= 1) {
    float mo = __shfl_xor(mx, o), so = __shfl_xor(sm, o);
    float nm = fmaxf(mx, mo);
    sm = sm * expf(mx - nm) + so * expf(mo - nm);
    mx = nm;
  }
  __shared__ float wm[4], wsum[4];
  __shared__ float srs;
  if ((tid & 63) == 0) { wm[tid >> 6] = mx; wsum[tid >> 6] = sm; }
  __syncthreads();
  if (tid == 0) {
    float M = wm[0], S = wsum[0];
    for (int i = 1; i < 4; i++) {
      float nm = fmaxf(M, wm[i]);
      S = S * expf(M - nm) + wsum[i] * expf(wm[i] - nm);
      M = nm;
    }
    srs = M + logf(S);
  }
  __syncthreads();
  const float rs = srs;
  for (int i = tid * 4; i < 21128; i += 1024) {
    float4 v = *(const float4*)(row + i);
    v.x -= rs; v.y -= rs; v.z -= rs; v.w -= rs;
    *(float4*)(row + i) = v;
  }
}

// ---------------------------------------------------------------------------
extern "C" void kernel_launch(void* const* d_in, const int* in_sizes, int n_in,
                              void* d_out, int out_size, void* d_ws, size_t ws_size,
                              hipStream_t stream) {
  (void)in_sizes; (void)n_in; (void)out_size; (void)ws_size;
  const int*   input_edits = (const int*)d_in[0];
  const int*   org_ids     = (const int*)d_in[1];
  const int*   simp_sent   = (const int*)d_in[2];
  const float* h0      = (const float*)d_in[3];
  const float* c0      = (const float*)d_in[4];
  const float* encoder = (const float*)d_in[5];
  const float* emb     = (const float*)d_in[6];
  const float* Wih_e   = (const float*)d_in[7];
  const float* Whh_e   = (const float*)d_in[8];
  const float* b_e     = (const float*)d_in[9];
  const float* Wih_w   = (const float*)d_in[10];
  const float* Whh_w   = (const float*)d_in[11];
  const float* b_w     = (const float*)d_in[12];
  const float* W_attn  = (const float*)d_in[13];
  const float* W_align = (const float*)d_in[14];
  const float* W_mlp   = (const float*)d_in[15];
  const float* b_mlp   = (const float*)d_in[16];
  const float* W_out   = (const float*)d_in[17];
  const float* b_out   = (const float*)d_in[18];

  float* out = (float*)d_out;
  // --- d_out region doubles as scratch until the logits GEMM overwrites it
  float* xW_e = out;                               // [2048][3072] f32
  float* xW_w = out + 2048L * 3072;                // [2056][3072] f32
  u16* emb_bf  = (u16*)(out + 2048L * 3072 + 2056L * 3072);  // [21128][768]
  u16* encd_bf = emb_bf + 21128L * 768;            // [2176][768] (pad rows 0)
  u16* feat_bf = encd_bf + 2176L * 768;            // [2048][3072]

  // --- ws scratch
  char* p = (char*)d_ws;
  auto alloc = [&](size_t bytes) -> char* {
    char* r = p; p += (bytes + 255) & ~(size_t)255; return r;
  };
  u16* Wout_bf   = (u16*)alloc(21248L * 768 * 2);
  u16* Wihe_bf   = (u16*)alloc(3072L * 768 * 2);
  u16* Wihw_bf   = (u16*)alloc(3072L * 768 * 2);
  u16* Wmlp_bf   = (u16*)alloc(768L * 3072 * 2);
  u16* Walign_bf = (u16*)alloc(768L * 768 * 2);
  u16* Wattn_bf  = (u16*)alloc(768L * 768 * 2);
  u16* enc_bf    = (u16*)alloc(8L * 384 * 768 * 2);   // padded batch stride
  u16* encT_bf   = (u16*)alloc(8L * 768 * 288 * 2);   // K padded to 288
  u16* oute_bf   = (u16*)alloc(2048L * 768 * 2);
  u16* outw_bf   = (u16*)alloc(2048L * 768 * 2);
  u16* key_bf    = (u16*)alloc(2048L * 768 * 2);
  u16* attn_bf   = (u16*)alloc(8L * 256 * 288 * 2);
  u16* ctx_bf    = (u16*)alloc(2048L * 768 * 2);
  u16* mlp_bf    = (u16*)alloc(2048L * 768 * 2);
  float* scores  = (float*)alloc(8L * 256 * 288 * 4);
  u16* hglob     = (u16*)alloc(2L * 2 * 2 * 16 * 768 * 2);  // [l][buf][part][16][768]
  unsigned int* ctr = (unsigned int*)alloc(256);
  int* ki_bt     = (int*)alloc(2040 * 4);
  int* an_bt     = (int*)alloc(2040 * 4);

  dim3 blk(256);
  const int BIGR = 1 << 30;

  // --- all casts in one dispatch; counters + barrier-counter zero in another
  cast_all<<<53000, blk, 0, stream>>>(emb, emb_bf, W_out, Wout_bf,
                                      Wih_e, Wihe_bf, Wih_w, Wihw_bf,
                                      W_mlp, Wmlp_bf, W_align, Walign_bf,
                                      W_attn, Wattn_bf, encoder, encd_bf);
  counters_k<<<1, 64, 0, stream>>>(input_edits, org_ids, ki_bt, an_bt, ctr);

  // --- enc = tanh(encoder @ W_align^T) -> bf16, padded [8][384][768] layout
  gemm_bt<1, 0, 1, 0><<<dim3(6, 17, 1), blk, 0, stream>>>(
      encd_bf, Walign_bf, nullptr, enc_bf, nullptr,
      2056, 768, 768, 768, 768, 768, 0, 0, 0, 257, 294912L);

  // --- hoisted LSTM input projections (embedding gather + bias)
  gemm_bt<0, 1, 0, 1><<<dim3(24, 16, 1), blk, 0, stream>>>(
      emb_bf, Wihe_bf, b_e, xW_e, input_edits,
      2048, 3072, 768, 768, 768, 3072, 0, 0, 0, BIGR, 0);
  gemm_bt<0, 1, 0, 1><<<dim3(24, 17, 1), blk, 0, stream>>>(
      emb_bf, Wihw_bf, b_w, xW_w, simp_sent,
      2056, 3072, 768, 768, 768, 3072, 0, 0, 0, BIGR, 0);

  // --- both recurrences, one persistent dispatch
  lstm_persist<<<96, blk, 0, stream>>>(
      Whh_e, Whh_w, xW_e, xW_w, h0, c0, hglob, ctr,
      oute_bf, outw_bf, out);

  // --- attention
  gemm_bt<1, 0, 0, 0><<<dim3(6, 16, 1), blk, 0, stream>>>(
      oute_bf, Wattn_bf, nullptr, key_bf, nullptr,
      2048, 768, 768, 768, 768, 768, 0, 0, 0, BIGR, 0);
  gemm_bt<0, 0, 0, 0><<<dim3(3, 2, 8), blk, 0, stream>>>(
      key_bf, enc_bf, nullptr, scores, nullptr,
      256, 257, 768, 768, 768, 288, 196608L, 294912L, 73728L, BIGR, 0);
  softmax_k<<<2048, blk, 0, stream>>>(scores, attn_bf);
  transpose_enc<<<dim3(9, 24, 8), blk, 0, stream>>>(enc_bf, encT_bf);
  gemm_bt<1, 0, 0, 0><<<dim3(6, 2, 8), blk, 0, stream>>>(
      attn_bf, encT_bf, nullptr, ctx_bf, nullptr,
      256, 768, 288, 288, 288, 768, 73728L, 221184L, 196608L, BIGR, 0);

  // --- feature concat + MLP + output projection
  feat_k<<<6144, blk, 0, stream>>>(oute_bf, ctx_bf, enc_bf, outw_bf,
                                   ki_bt, an_bt, feat_bf);
  gemm_bt<1, 0, 1, 1><<<dim3(6, 16, 1), blk, 0, stream>>>(
      feat_bf, Wmlp_bf, b_mlp, mlp_bf, nullptr,
      2040, 768, 3072, 3072, 3072, 768, 0, 0, 0, BIGR, 0);
  gemm_bt<0, 0, 0, 1><<<dim3(166, 16, 1), blk, 0, stream>>>(
      mlp_bf, Wout_bf, b_out, out, nullptr,
      2040, 21128, 768, 768, 768, 21128, 0, 0, 0, BIGR, 0);

  // --- fused log_softmax (in place)
  logsoftmax_k<<<2040, blk, 0, stream>>>(out);
}

// Round 4
// 1820.331 us; speedup vs baseline: 2.6384x; 1.7773x over previous
//
#include <hip/hip_runtime.h>
#include <hip/hip_bf16.h>

typedef short s16x8 __attribute__((ext_vector_type(8)));
typedef float f32x4 __attribute__((ext_vector_type(4)));
typedef unsigned short u16;
typedef unsigned short u16x4 __attribute__((ext_vector_type(4)));

__device__ __forceinline__ u16 f2bf(float f) {
  __hip_bfloat16 h = __float2bfloat16(f);
  u16 u;
  __builtin_memcpy(&u, &h, sizeof(u));
  return u;
}
__device__ __forceinline__ float bf2f(u16 u) {
  unsigned int x = ((unsigned int)u) << 16;
  float f;
  __builtin_memcpy(&f, &x, 4);
  return f;
}

// async global->LDS, 16B per lane; lds addr must be wave-uniform base
__device__ __forceinline__ void gload16(const void* g, void* l) {
  __builtin_amdgcn_global_load_lds(
      (const __attribute__((address_space(1))) unsigned int*)g,
      (__attribute__((address_space(3))) unsigned int*)l, 16, 0, 0);
}

// ---------------------------------------------------------------------------
// Generic bf16 MFMA GEMM:  C[m,n] = act( sum_k A[m,k]*B[n,k] + bias[n] )
// 128x128 tile, BK=32, 256 threads. Staging via global_load_lds width-16.
// ---------------------------------------------------------------------------
template<int CBF16, int GATHER, int TANHA, int BIAS>
__global__ __launch_bounds__(256) void gemm_bt(
    const u16* __restrict__ A, const u16* __restrict__ B,
    const float* __restrict__ bias, void* __restrict__ Cv,
    const int* __restrict__ ids,
    int M, int N, int K, int lda, int ldb, int ldc,
    long sAz, long sBz, long sCz, int rpb, long cbs)
{
  __shared__ u16 sA[4096];
  __shared__ u16 sB[4096];
  const int tid = threadIdx.x;
  const int z = blockIdx.z;
  const int m0 = blockIdx.y * 128, n0 = blockIdx.x * 128;
  const u16* Ab = A + z * sAz;
  const u16* Bb = B + z * sBz;
  const int w = tid >> 6, lane = tid & 63;
  const int wr = w >> 1, wc = w & 1;
  const int lr = lane & 15, lk = lane >> 4;
  f32x4 acc[4][4] = {};
  const int e0 = tid * 8, e1 = e0 + 2048;
  const int r0 = e0 >> 5, c0 = e0 & 31;
  const int r1 = e1 >> 5, c1 = e1 & 31;
  long arow0, arow1;
  if (GATHER) {
    int i0 = m0 + r0; if (i0 >= M) i0 = M - 1;
    int i1 = m0 + r1; if (i1 >= M) i1 = M - 1;
    arow0 = (long)ids[i0] * lda;
    arow1 = (long)ids[i1] * lda;
  } else {
    arow0 = (long)(m0 + r0) * lda;
    arow1 = (long)(m0 + r1) * lda;
  }
  const long brow0 = (long)(n0 + r0) * ldb;
  const long brow1 = (long)(n0 + r1) * ldb;
  char* sAc = (char*)sA;
  char* sBc = (char*)sB;
  const size_t cb = (size_t)w * 1024;
  for (int kt = 0; kt < K; kt += 32) {
    __syncthreads();
    gload16(Ab + arow0 + kt + c0, sAc + cb);
    gload16(Ab + arow1 + kt + c1, sAc + 4096 + cb);
    gload16(Bb + brow0 + kt + c0, sBc + cb);
    gload16(Bb + brow1 + kt + c1, sBc + 4096 + cb);
    __syncthreads();
    s16x8 af[4], bf[4];
#pragma unroll
    for (int i = 0; i < 4; i++) {
      af[i] = *(const s16x8*)&sA[(wr*64 + i*16 + lr)*32 + lk*8];
      bf[i] = *(const s16x8*)&sB[(wc*64 + i*16 + lr)*32 + lk*8];
    }
#pragma unroll
    for (int mi = 0; mi < 4; mi++)
#pragma unroll
      for (int ni = 0; ni < 4; ni++)
        acc[mi][ni] = __builtin_amdgcn_mfma_f32_16x16x32_bf16(af[mi], bf[ni], acc[mi][ni], 0, 0, 0);
  }
#pragma unroll
  for (int mi = 0; mi < 4; mi++) {
#pragma unroll
    for (int ni = 0; ni < 4; ni++) {
#pragma unroll
      for (int r = 0; r < 4; r++) {
        int gm = m0 + wr*64 + mi*16 + lk*4 + r;
        int gn = n0 + wc*64 + ni*16 + lr;
        if (gm < M && gn < N) {
          float v = acc[mi][ni][r];
          if (BIAS) v += bias[gn];
          if (TANHA) v = tanhf(v);
          long ci = z * sCz + (long)(gm / rpb) * cbs + (long)(gm % rpb) * ldc + gn;
          if (CBF16) ((u16*)Cv)[ci] = f2bf(v);
          else       ((float*)Cv)[ci] = v;
        }
      }
    }
  }
}

// ---------------------------------------------------------------------------
// All fp32->bf16 casts in one dispatch. One block per destination row.
// ---------------------------------------------------------------------------
__global__ __launch_bounds__(256) void cast_all(
    const float* __restrict__ emb, u16* __restrict__ emb_bf,
    const float* __restrict__ Wout, u16* __restrict__ Wout_bf,
    const float* __restrict__ Wihe, u16* __restrict__ Wihe_bf,
    const float* __restrict__ Wihw, u16* __restrict__ Wihw_bf,
    const float* __restrict__ Wmlp, u16* __restrict__ Wmlp_bf,
    const float* __restrict__ Walign, u16* __restrict__ Walign_bf,
    const float* __restrict__ Wattn, u16* __restrict__ Wattn_bf,
    const float* __restrict__ encoder, u16* __restrict__ encd_bf)
{
  int r = blockIdx.x;
  const float* src; u16* dst; int srows, cols;
  if (r < 21128)                    { src=emb;    dst=emb_bf;    srows=21128; cols=768; }
  else if ((r -= 21128) < 21248)    { src=Wout;   dst=Wout_bf;   srows=21128; cols=768; }
  else if ((r -= 21248) < 3072)     { src=Wihe;   dst=Wihe_bf;   srows=3072;  cols=768; }
  else if ((r -= 3072) < 3072)      { src=Wihw;   dst=Wihw_bf;   srows=3072;  cols=768; }
  else if ((r -= 3072) < 768)       { src=Wmlp;   dst=Wmlp_bf;   srows=768;   cols=3072; }
  else if ((r -= 768) < 768)        { src=Walign; dst=Walign_bf; srows=768;   cols=768; }
  else if ((r -= 768) < 768)        { src=Wattn;  dst=Wattn_bf;  srows=768;   cols=768; }
  else { r -= 768;                    src=encoder; dst=encd_bf;  srows=2056;  cols=768; }
  for (int c = threadIdx.x; c < cols; c += 256) {
    float v = (r < srows) ? src[(long)r * cols + c] : 0.f;
    dst[(long)r * cols + c] = f2bf(v);
  }
}

// counter recurrence (8 lanes) + zero the persistent-kernel barrier counters
__global__ void counters_k(const int* __restrict__ input_edits,
                           const int* __restrict__ org_ids,
                           int* __restrict__ ki_bt, int* __restrict__ an_bt,
                           unsigned int* __restrict__ ctr)
{
  int b = threadIdx.x;
  if (b == 8) { ctr[0] = 0; ctr[1] = 0; }
  if (b >= 8) return;
  int kd = 0, ki = 0, an = 0;
  for (int t = 0; t < 255; t++) {
    int a = input_edits[b * 256 + t + 1];
    ki_bt[b * 255 + t] = ki;
    an_bt[b * 255 + t] = an;
    int kd2 = kd + ((a == 1) || (a == 2) ? 1 : 0);
    int ns = (a != 2) && (a != 102) && (a != 0);
    int ki2 = ki + (ns ? 1 : 0);
    int is_ins = ns && (a != 1);
    int nia = (org_ids[b * 257 + an + 1] == 103);
    int mx = (kd2 > an) ? kd2 : an;
    int an2 = (is_ins && nia) ? (an + 1) : mx;
    kd = kd2; ki = ki2; an = an2;
  }
}

// device-scope group barrier: RELEASE arrive, RELAXED spin (no per-poll L2
// inv), single ACQUIRE fence after detection. Counter zeroed by counters_k.
__device__ __forceinline__ void grp_barrier(unsigned int* c, unsigned int target) {
  __syncthreads();
  if (threadIdx.x == 0) {
    __hip_atomic_fetch_add(c, 1u, __ATOMIC_RELEASE, __HIP_MEMORY_SCOPE_AGENT);
    while (__hip_atomic_load(c, __ATOMIC_RELAXED, __HIP_MEMORY_SCOPE_AGENT) < target)
      __builtin_amdgcn_s_sleep(1);
    __builtin_amdgcn_fence(__ATOMIC_ACQUIRE, "agent");
  }
  __syncthreads();
}

// ---------------------------------------------------------------------------
// Persistent LSTM: 48 WGs = 2 LSTMs x 24 groups (32 units each). W held in
// VGPRs as MFMA B-frags (wave w: unit-half w>>1, gates (w&1)*2+{0,1}; 2x24
// slabs = 192 VGPR/lane). h as hi/lo residual bf16 packed into rows 0-7/8-15
// of ONE 16-row A-tile (one MFMA chain computes hi*W and lo*W; updater sums
// C[b]+C[b+8]). h exchanged via swizzled global buffer (24 KB/step), staged
// with global_load_lds; xW(t+1) prefetched into regs before the barrier.
// ---------------------------------------------------------------------------
__global__ __launch_bounds__(256, 1) void lstm_persist(
    const float* __restrict__ Whh_e, const float* __restrict__ Whh_w,
    const float* __restrict__ xW_e, const float* __restrict__ xW_w,
    const float* __restrict__ h0, const float* __restrict__ c0,
    u16* __restrict__ hglob, unsigned int* __restrict__ ctr,
    u16* __restrict__ out_e, u16* __restrict__ out_w,
    float* __restrict__ out_tail)
{
  const int wg = blockIdx.x;
  const int l = wg / 24, grp = wg % 24;
  const int u0 = grp * 32;
  const int tid = threadIdx.x;
  const int w = tid >> 6, lane = tid & 63;
  const int c16 = lane & 15, half = lane >> 4;
  const int uh = w >> 1, g0 = (w & 1) * 2;

  __shared__ u16 ldsh[12288];          // [16][768] swizzled (24 KB)
  __shared__ float Gbuf[16][4][2][16]; // [row][gate][uh][unit-col] (8 KB)

  // ---- persistent W fragments (B-frag per (gate,s)): lane (c16,half) holds
  // W[(g0+g)*768 + u0 + uh*16 + c16][s*32 + half*8 .. +8] as bf16
  s16x8 wfrag[2][24];
  {
    const float* Wbase = l ? Whh_w : Whh_e;
#pragma unroll
    for (int g = 0; g < 2; g++) {
      const float* Wsrc = Wbase + (long)((g0 + g) * 768 + u0 + uh * 16 + c16) * 768 + half * 8;
#pragma unroll
      for (int s = 0; s < 24; s++) {
        float4 f0 = *(const float4*)(Wsrc + s * 32);
        float4 f1 = *(const float4*)(Wsrc + s * 32 + 4);
        s16x8 v;
        v[0]=f2bf(f0.x); v[1]=f2bf(f0.y); v[2]=f2bf(f0.z); v[3]=f2bf(f0.w);
        v[4]=f2bf(f1.x); v[5]=f2bf(f1.y); v[6]=f2bf(f1.z); v[7]=f2bf(f1.w);
        wfrag[g][s] = v;
      }
    }
  }

  // ---- updater identity: tid -> (batch ub, unit offset uu)
  const int ub = tid >> 5, uu = tid & 31;
  const int u = u0 + uu;
  float creg = c0[ub * 768 + u];

  u16* hg = hglob + l * 24576;         // [buf2][16][768]
  // ---- h0 init: hi rows 0-7, lo rows 8-15, swizzled for LDS A-frag reads
  if (grp == 0) {
    for (int i = tid; i < 6144; i += 256) {
      int b = i / 768, uc = i - b * 768;
      float v = h0[i];
      u16 hi = f2bf(v);
      u16 lo = f2bf(v - bf2f(hi));
      int sw = uc ^ ((b & 7) << 3);
      hg[b * 768 + sw] = hi;
      hg[(b + 8) * 768 + sw] = lo;
    }
  }
  grp_barrier(ctr + l, 24u);

  const float* xrb = (l ? xW_w : xW_e) + (long)ub * (l ? 257 : 256) * 3072 + u;
  u16* outp = (l ? out_w : out_e) + (long)ub * 256 * 768 + u;
  float xq0 = xrb[0], xq1 = xrb[768], xq2 = xrb[1536], xq3 = xrb[2304];

  for (int t = 0; t < 256; t++) {
    // stage h buf(t&1) -> LDS, 24 KB in 6 rounds (identity copy)
    const u16* hsrc = hg + (t & 1) * 12288;
    char* lb = (char*)ldsh;
#pragma unroll
    for (int i = 0; i < 6; i++)
      gload16(hsrc + (i * 256 + tid) * 8, lb + (i * 256 + w * 64) * 16);

    // prefetch next-step xW while loads/MFMA run (off the critical path)
    float nx0 = 0.f, nx1 = 0.f, nx2 = 0.f, nx3 = 0.f;
    if (t + 1 < 256) {
      const float* xn = xrb + (long)(t + 1) * 3072;
      nx0 = xn[0]; nx1 = xn[768]; nx2 = xn[1536]; nx3 = xn[2304];
    }
    __syncthreads();

    f32x4 acc0 = {}, acc1 = {};
#pragma unroll
    for (int s = 0; s < 24; s++) {
      const int off = (c16 * 768 + s * 32 + half * 8) ^ ((c16 & 7) << 3);
      s16x8 a = *(const s16x8*)&ldsh[off];
      acc0 = __builtin_amdgcn_mfma_f32_16x16x32_bf16(a, wfrag[0][s], acc0, 0, 0, 0);
      acc1 = __builtin_amdgcn_mfma_f32_16x16x32_bf16(a, wfrag[1][s], acc1, 0, 0, 0);
    }
#pragma unroll
    for (int r = 0; r < 4; r++) {
      Gbuf[half * 4 + r][g0 + 0][uh][c16] = acc0[r];
      Gbuf[half * 4 + r][g0 + 1][uh][c16] = acc1[r];
    }
    __syncthreads();

    {
      const int uhh = uu >> 4, uc = uu & 15;
      float gi = Gbuf[ub][0][uhh][uc] + Gbuf[ub + 8][0][uhh][uc] + xq0;
      float gf = Gbuf[ub][1][uhh][uc] + Gbuf[ub + 8][1][uhh][uc] + xq1;
      float gg = Gbuf[ub][2][uhh][uc] + Gbuf[ub + 8][2][uhh][uc] + xq2;
      float go = Gbuf[ub][3][uhh][uc] + Gbuf[ub + 8][3][uhh][uc] + xq3;
      float si = 1.f / (1.f + expf(-gi));
      float sf = 1.f / (1.f + expf(-gf));
      float so = 1.f / (1.f + expf(-go));
      float c2 = sf * creg + si * tanhf(gg);
      float h2 = so * tanhf(c2);
      creg = c2;
      u16 hi = f2bf(h2);
      u16 lo = f2bf(h2 - bf2f(hi));
      const int sw = u ^ ((ub & 7) << 3);
      u16* hb = hg + ((t + 1) & 1) * 12288;
      hb[ub * 768 + sw] = hi;
      hb[(ub + 8) * 768 + sw] = lo;
      outp[(long)t * 768] = hi;
      if (l == 0 && t == 255) {
        out_tail[43101120 + ub * 768 + u] = h2;
        out_tail[43107264 + ub * 768 + u] = c2;
      }
    }
    xq0 = nx0; xq1 = nx1; xq2 = nx2; xq3 = nx3;
    grp_barrier(ctr + l, 24u * (t + 2));
  }
}

// softmax over s (257 valid of 288) per (b,t) row; writes bf16 attn, zero pad
__global__ __launch_bounds__(256) void softmax_k(
    const float* __restrict__ scores, u16* __restrict__ attn)
{
  const int row = blockIdx.x;                 // 0..2047
  const float* src = scores + (long)row * 288;
  u16* dst = attn + (long)row * 288;
  const int tid = threadIdx.x;
  float v0 = (tid < 257) ? src[tid] : -1e30f;
  float v1 = (tid + 256 < 257) ? src[tid + 256] : -1e30f;
  float mx = fmaxf(v0, v1);
  for (int o = 32; o; o >>= 1) mx = fmaxf(mx, __shfl_xor(mx, o));
  __shared__ float sm[4];
  __shared__ float ss[4];
  if ((tid & 63) == 0) sm[tid >> 6] = mx;
  __syncthreads();
  mx = fmaxf(fmaxf(sm[0], sm[1]), fmaxf(sm[2], sm[3]));
  float e0 = (tid < 257) ? expf(v0 - mx) : 0.f;
  float e1 = (tid + 256 < 257) ? expf(v1 - mx) : 0.f;
  float s = e0 + e1;
  for (int o = 32; o; o >>= 1) s += __shfl_xor(s, o);
  if ((tid & 63) == 0) ss[tid >> 6] = s;
  __syncthreads();
  s = ss[0] + ss[1] + ss[2] + ss[3];
  float inv = 1.f / s;
  dst[tid] = f2bf(e0 * inv);
  if (tid + 256 < 288) dst[tid + 256] = f2bf(e1 * inv);
}

// enc_bf [8][384][768] -> encT_bf [8][768][288] (zero pad s>=257)
__global__ __launch_bounds__(256) void transpose_enc(
    const u16* __restrict__ enc, u16* __restrict__ encT)
{
  __shared__ u16 tile[32][33];
  const int b = blockIdx.z, h0 = blockIdx.y * 32, s0 = blockIdx.x * 32;
  const int tx = threadIdx.x & 31, ty = threadIdx.x >> 5;  // ty 0..7
#pragma unroll
  for (int i = 0; i < 32; i += 8) {
    int s = s0 + ty + i;
    u16 v = (s < 257) ? enc[((long)b * 384 + s) * 768 + h0 + tx] : (u16)0;
    tile[ty + i][tx] = v;
  }
  __syncthreads();
#pragma unroll
  for (int i = 0; i < 32; i += 8) {
    int h = h0 + ty + i;
    encT[((long)b * 768 + h) * 288 + s0 + tx] = tile[tx][ty + i];
  }
}

// feat[2048][3072] bf16 = [out_edits | ctx | enc(an) | out_words(ki)], 0-pad
__global__ __launch_bounds__(256) void feat_k(
    const u16* __restrict__ oute, const u16* __restrict__ ctx,
    const u16* __restrict__ encb, const u16* __restrict__ outw,
    const int* __restrict__ ki_bt, const int* __restrict__ an_bt,
    u16* __restrict__ feat)
{
  int q = blockIdx.x * 256 + threadIdx.x;       // < 1572864 (u16x4 units)
  int m = q / 768, qq = q - m * 768;
  int seg = qq / 192, off = (qq - seg * 192) * 4;
  u16x4 v = {0, 0, 0, 0};
  if (m < 2040) {
    int b = m / 255, t = m - b * 255;
    const u16* src;
    if (seg == 0)      src = oute + ((long)(b * 256 + t)) * 768 + off;
    else if (seg == 1) src = ctx  + ((long)(b * 256 + t)) * 768 + off;
    else if (seg == 2) src = encb + ((long)(b * 384 + an_bt[m])) * 768 + off;
    else               src = outw + ((long)(b * 256 + ki_bt[m])) * 768 + off;
    v = *(const u16x4*)src;
  }
  *(u16x4*)(feat + (long)q * 4) = v;
}

// fused log_softmax: per-row stat then in-place subtract (row stays in L2)
__global__ __launch_bounds__(256) void logsoftmax_k(float* __restrict__ logits)
{
  const int m = blockIdx.x;
  float* row = logits + (long)m * 21128;
  const int tid = threadIdx.x;
  float mx = -1e30f, sm = 0.f;
  for (int i = tid * 4; i < 21128; i += 1024) {
    float4 v = *(const float4*)(row + i);
    float m4 = fmaxf(fmaxf(v.x, v.y), fmaxf(v.z, v.w));
    if (m4 > mx) { sm *= expf(mx - m4); mx = m4; }
    sm += expf(v.x - mx) + expf(v.y - mx) + expf(v.z - mx) + expf(v.w - mx);
  }
  for (int o = 32; o; o >>= 1) {
    float mo = __shfl_xor(mx, o), so = __shfl_xor(sm, o);
    float nm = fmaxf(mx, mo);
    sm = sm * expf(mx - nm) + so * expf(mo - nm);
    mx = nm;
  }
  __shared__ float wm[4], wsum[4];
  __shared__ float srs;
  if ((tid & 63) == 0) { wm[tid >> 6] = mx; wsum[tid >> 6] = sm; }
  __syncthreads();
  if (tid == 0) {
    float M = wm[0], S = wsum[0];
    for (int i = 1; i < 4; i++) {
      float nm = fmaxf(M, wm[i]);
      S = S * expf(M - nm) + wsum[i] * expf(wm[i] - nm);
      M = nm;
    }
    srs = M + logf(S);
  }
  __syncthreads();
  const float rs = srs;
  for (int i = tid * 4; i < 21128; i += 1024) {
    float4 v = *(const float4*)(row + i);
    v.x -= rs; v.y -= rs; v.z -= rs; v.w -= rs;
    *(float4*)(row + i) = v;
  }
}

// ---------------------------------------------------------------------------
extern "C" void kernel_launch(void* const* d_in, const int* in_sizes, int n_in,
                              void* d_out, int out_size, void* d_ws, size_t ws_size,
                              hipStream_t stream) {
  (void)in_sizes; (void)n_in; (void)out_size; (void)ws_size;
  const int*   input_edits = (const int*)d_in[0];
  const int*   org_ids     = (const int*)d_in[1];
  const int*   simp_sent   = (const int*)d_in[2];
  const float* h0      = (const float*)d_in[3];
  const float* c0      = (const float*)d_in[4];
  const float* encoder = (const float*)d_in[5];
  const float* emb     = (const float*)d_in[6];
  const float* Wih_e   = (const float*)d_in[7];
  const float* Whh_e   = (const float*)d_in[8];
  const float* b_e     = (const float*)d_in[9];
  const float* Wih_w   = (const float*)d_in[10];
  const float* Whh_w   = (const float*)d_in[11];
  const float* b_w     = (const float*)d_in[12];
  const float* W_attn  = (const float*)d_in[13];
  const float* W_align = (const float*)d_in[14];
  const float* W_mlp   = (const float*)d_in[15];
  const float* b_mlp   = (const float*)d_in[16];
  const float* W_out   = (const float*)d_in[17];
  const float* b_out   = (const float*)d_in[18];

  float* out = (float*)d_out;
  // --- d_out region doubles as scratch until the logits GEMM overwrites it
  float* xW_e = out;                               // [2048][3072] f32
  float* xW_w = out + 2048L * 3072;                // [2056][3072] f32
  u16* emb_bf  = (u16*)(out + 2048L * 3072 + 2056L * 3072);  // [21128][768]
  u16* encd_bf = emb_bf + 21128L * 768;            // [2176][768] (pad rows 0)
  u16* feat_bf = encd_bf + 2176L * 768;            // [2048][3072]

  // --- ws scratch
  char* p = (char*)d_ws;
  auto alloc = [&](size_t bytes) -> char* {
    char* r = p; p += (bytes + 255) & ~(size_t)255; return r;
  };
  u16* Wout_bf   = (u16*)alloc(21248L * 768 * 2);
  u16* Wihe_bf   = (u16*)alloc(3072L * 768 * 2);
  u16* Wihw_bf   = (u16*)alloc(3072L * 768 * 2);
  u16* Wmlp_bf   = (u16*)alloc(768L * 3072 * 2);
  u16* Walign_bf = (u16*)alloc(768L * 768 * 2);
  u16* Wattn_bf  = (u16*)alloc(768L * 768 * 2);
  u16* enc_bf    = (u16*)alloc(8L * 384 * 768 * 2);   // padded batch stride
  u16* encT_bf   = (u16*)alloc(8L * 768 * 288 * 2);   // K padded to 288
  u16* oute_bf   = (u16*)alloc(2048L * 768 * 2);
  u16* outw_bf   = (u16*)alloc(2048L * 768 * 2);
  u16* key_bf    = (u16*)alloc(2048L * 768 * 2);
  u16* attn_bf   = (u16*)alloc(8L * 256 * 288 * 2);
  u16* ctx_bf    = (u16*)alloc(2048L * 768 * 2);
  u16* mlp_bf    = (u16*)alloc(2048L * 768 * 2);
  float* scores  = (float*)alloc(8L * 256 * 288 * 4);
  u16* hglob     = (u16*)alloc(2L * 2 * 12288 * 2);   // [l][buf][16][768]
  unsigned int* ctr = (unsigned int*)alloc(256);
  int* ki_bt     = (int*)alloc(2040 * 4);
  int* an_bt     = (int*)alloc(2040 * 4);

  dim3 blk(256);
  const int BIGR = 1 << 30;

  // --- all casts in one dispatch; counters + barrier-counter zero in another
  cast_all<<<53000, blk, 0, stream>>>(emb, emb_bf, W_out, Wout_bf,
                                      Wih_e, Wihe_bf, Wih_w, Wihw_bf,
                                      W_mlp, Wmlp_bf, W_align, Walign_bf,
                                      W_attn, Wattn_bf, encoder, encd_bf);
  counters_k<<<1, 64, 0, stream>>>(input_edits, org_ids, ki_bt, an_bt, ctr);

  // --- enc = tanh(encoder @ W_align^T) -> bf16, padded [8][384][768] layout
  gemm_bt<1, 0, 1, 0><<<dim3(6, 17, 1), blk, 0, stream>>>(
      encd_bf, Walign_bf, nullptr, enc_bf, nullptr,
      2056, 768, 768, 768, 768, 768, 0, 0, 0, 257, 294912L);

  // --- hoisted LSTM input projections (embedding gather + bias)
  gemm_bt<0, 1, 0, 1><<<dim3(24, 16, 1), blk, 0, stream>>>(
      emb_bf, Wihe_bf, b_e, xW_e, input_edits,
      2048, 3072, 768, 768, 768, 3072, 0, 0, 0, BIGR, 0);
  gemm_bt<0, 1, 0, 1><<<dim3(24, 17, 1), blk, 0, stream>>>(
      emb_bf, Wihw_bf, b_w, xW_w, simp_sent,
      2056, 3072, 768, 768, 768, 3072, 0, 0, 0, BIGR, 0);

  // --- both recurrences, one persistent dispatch (48 WGs)
  lstm_persist<<<48, blk, 0, stream>>>(
      Whh_e, Whh_w, xW_e, xW_w, h0, c0, hglob, ctr,
      oute_bf, outw_bf, out);

  // --- attention
  gemm_bt<1, 0, 0, 0><<<dim3(6, 16, 1), blk, 0, stream>>>(
      oute_bf, Wattn_bf, nullptr, key_bf, nullptr,
      2048, 768, 768, 768, 768, 768, 0, 0, 0, BIGR, 0);
  gemm_bt<0, 0, 0, 0><<<dim3(3, 2, 8), blk, 0, stream>>>(
      key_bf, enc_bf, nullptr, scores, nullptr,
      256, 257, 768, 768, 768, 288, 196608L, 294912L, 73728L, BIGR, 0);
  softmax_k<<<2048, blk, 0, stream>>>(scores, attn_bf);
  transpose_enc<<<dim3(9, 24, 8), blk, 0, stream>>>(enc_bf, encT_bf);
  gemm_bt<1, 0, 0, 0><<<dim3(6, 2, 8), blk, 0, stream>>>(
      attn_bf, encT_bf, nullptr, ctx_bf, nullptr,
      256, 768, 288, 288, 288, 768, 73728L, 221184L, 196608L, BIGR, 0);

  // --- feature concat + MLP + output projection
  feat_k<<<6144, blk, 0, stream>>>(oute_bf, ctx_bf, enc_bf, outw_bf,
                                   ki_bt, an_bt, feat_bf);
  gemm_bt<1, 0, 1, 1><<<dim3(6, 16, 1), blk, 0, stream>>>(
      feat_bf, Wmlp_bf, b_mlp, mlp_bf, nullptr,
      2040, 768, 3072, 3072, 3072, 768, 0, 0, 0, BIGR, 0);
  gemm_bt<0, 0, 0, 1><<<dim3(166, 16, 1), blk, 0, stream>>>(
      mlp_bf, Wout_bf, b_out, out, nullptr,
      2040, 21128, 768, 768, 768, 21128, 0, 0, 0, BIGR, 0);

  // --- fused log_softmax (in place)
  logsoftmax_k<<<2040, blk, 0, stream>>>(out);
}